// Round 1
// baseline (470.471 us; speedup 1.0000x reference)
//
#include <hip/hip_runtime.h>
#include <hip/hip_bf16.h>

#define BS   8
#define TT   1024
#define DIN  64
#define NH   8
#define DOUT 1024

typedef __attribute__((ext_vector_type(8))) short bf16x8;
typedef __attribute__((ext_vector_type(8))) unsigned short u16x8;
typedef __attribute__((ext_vector_type(4))) float f32x4;

__device__ __forceinline__ unsigned short f2bf(float f) {
    unsigned int u = __float_as_uint(f);
    u += 0x7fff + ((u >> 16) & 1);          // RNE
    return (unsigned short)(u >> 16);
}

// ---------------- Kernel 0: W_w (f32) -> bf16 ----------------
__global__ __launch_bounds__(256) void conv_w_kernel(const float* __restrict__ W,
                                                     unsigned short* __restrict__ Wb) {
    int i = blockIdx.x * 256 + threadIdx.x;            // float4 index, grid covers exactly
    float4 v = ((const float4*)W)[i];
    ushort4 o;
    o.x = f2bf(v.x); o.y = f2bf(v.y); o.z = f2bf(v.z); o.w = f2bf(v.w);
    ((ushort4*)Wb)[i] = o;
}

// ---------------- Kernel 1: q/k projection ----------------
// Q[row][16], K[b][h][l][2];  row = b*T + t  (8192 rows)
__global__ __launch_bounds__(256) void qk_prep(const float* __restrict__ X,
                                               const float* __restrict__ Wq_w,
                                               const float* __restrict__ Wq_b,
                                               const float* __restrict__ Wk_w,
                                               const float* __restrict__ Wk_b,
                                               float* __restrict__ Q,
                                               float* __restrict__ K) {
    __shared__ float Ws[32][65];
    __shared__ float bs[32];
    __shared__ float Xs[8][64];
    int tid = threadIdx.x;
    for (int i = tid; i < 2048; i += 256) {
        int r = i >> 6, d = i & 63;
        Ws[r][d] = (r < 16) ? Wq_w[r * 64 + d] : Wk_w[(r - 16) * 64 + d];
    }
    if (tid < 32) bs[tid] = (tid < 16) ? Wq_b[tid] : Wk_b[tid - 16];
    int row0 = blockIdx.x * 8;
    for (int i = tid; i < 512; i += 256) {
        int r = i >> 6, d = i & 63;
        Xs[r][d] = X[(size_t)(row0 + r) * 64 + d];
    }
    __syncthreads();
    int r = tid >> 5;       // 0..7
    int j = tid & 31;       // 0..31
    float s = bs[j];
    #pragma unroll
    for (int d = 0; d < 64; ++d) s = fmaf(Xs[r][d], Ws[j][d], s);
    int row = row0 + r;
    if (j < 16) {
        Q[(size_t)row * 16 + j] = s;
    } else {
        int h = (j - 16) >> 1, d2 = (j - 16) & 1;
        int b = row >> 10, l = row & 1023;
        K[(((size_t)(b * 8 + h)) * 1024 + l) * 2 + d2] = s;
    }
}

// ---------------- Kernel 2: fused scores+softmax+PV ----------------
// grid: (128 t-tiles, 8 batches), block 512 = 8 waves, wave = head.
// Each wave: 8 query rows, all 1024 keys. IV out: bf16 [b][c=h*64+d][t]
__global__ __launch_bounds__(512) void attn_kernel(const float* __restrict__ X,
                                                   const float* __restrict__ Q,
                                                   const float* __restrict__ K,
                                                   const float* __restrict__ u,
                                                   const float* __restrict__ Wkey,
                                                   const float* __restrict__ center,
                                                   const float* __restrict__ alpha,
                                                   unsigned short* __restrict__ IV) {
    const int b    = blockIdx.y;
    const int t0   = blockIdx.x * 8;
    const int tid  = threadIdx.x;
    const int h    = tid >> 6;
    const int lane = tid & 63;

    __shared__ float Xs[64][64];

    // per-t uniform coefficients
    const float al = alpha[0];
    const float v0 = -al;
    const float v1 = 2.0f * al * center[h];
    const float W00 = Wkey[0], W01 = Wkey[1], W10 = Wkey[2], W11 = Wkey[3];
    float a0[8], a1[8], c0[8], c1[8], tf[8];
    #pragma unroll
    for (int t = 0; t < 8; ++t) {
        int tg = t0 + t;
        float q0 = Q[(size_t)(b * 1024 + tg) * 16 + 2 * h];
        float q1 = Q[(size_t)(b * 1024 + tg) * 16 + 2 * h + 1];
        a0[t] = q0 + u[tg * 2];
        a1[t] = q1 + u[tg * 2 + 1];
        float p0 = q0 + v0, p1 = q1 + v1;
        c0[t] = p0 * W00 + p1 * W10;   // column e=0 of Wkey_
        c1[t] = p0 * W01 + p1 * W11;   // column e=1
        tf[t] = (float)tg;
    }

    const float2* K2 = (const float2*)(K + ((size_t)(b * 8 + h)) * 1024 * 2);

    // Pass A: row max
    float m[8];
    #pragma unroll
    for (int t = 0; t < 8; ++t) m[t] = -1e30f;
    for (int c = 0; c < 16; ++c) {
        int l = c * 64 + lane;
        float2 kk = K2[l];
        float fl = (float)l;
        #pragma unroll
        for (int t = 0; t < 8; ++t) {
            float dl = fl - tf[t];
            float s = fmaf(a0[t], kk.x, a1[t] * kk.y);
            s = fmaf(fmaf(c0[t], dl, c1[t]), dl, s);
            m[t] = fmaxf(m[t], s);
        }
    }
    #pragma unroll
    for (int t = 0; t < 8; ++t)
        for (int off = 32; off; off >>= 1)
            m[t] = fmaxf(m[t], __shfl_xor(m[t], off));

    float sum[8], iv[8];
    #pragma unroll
    for (int t = 0; t < 8; ++t) { sum[t] = 0.f; iv[t] = 0.f; }

    // Pass B: recompute scores -> e, PV with LDS-staged X
    for (int c = 0; c < 16; ++c) {
        __syncthreads();
        {
            const float4* Xg = (const float4*)(X + ((size_t)(b * 1024 + c * 64)) * 64);
            float4* Xsv = (float4*)(&Xs[0][0]);
            Xsv[tid]       = Xg[tid];
            Xsv[tid + 512] = Xg[tid + 512];
        }
        __syncthreads();
        float e[8];
        {
            int l = c * 64 + lane;
            float2 kk = K2[l];
            float fl = (float)l;
            #pragma unroll
            for (int t = 0; t < 8; ++t) {
                float dl = fl - tf[t];
                float s = fmaf(a0[t], kk.x, a1[t] * kk.y);
                s = fmaf(fmaf(c0[t], dl, c1[t]), dl, s);
                float ev = exp2f((s - m[t]) * 1.4426950408889634f);
                e[t] = ev;
                sum[t] += ev;
            }
        }
        #pragma unroll 4
        for (int ll = 0; ll < 64; ++ll) {
            float x = Xs[ll][lane];
            #pragma unroll
            for (int t = 0; t < 8; ++t) {
                float p = __uint_as_float(
                    __builtin_amdgcn_readlane(__float_as_uint(e[t]), ll));
                iv[t] = fmaf(p, x, iv[t]);
            }
        }
    }

    // normalize + store bf16, lane owns channel c = h*64+lane, 8 consecutive t
    u16x8 o;
    #pragma unroll
    for (int t = 0; t < 8; ++t) {
        float s = sum[t];
        for (int off = 32; off; off >>= 1) s += __shfl_xor(s, off);
        o[t] = f2bf(iv[t] * (1.0f / s));
    }
    *(u16x8*)(IV + ((size_t)(b * 512 + h * 64 + lane)) * 1024 + t0) = o;
}

// ---------------- Kernel 3: out = IV(bf16) @ W_w^T(bf16) + W_b, MFMA ----------------
// grid (8 j-tiles, 4 c-tiles, 8 b), block 256 = 4 waves (2x2 of 64x64)
__global__ __launch_bounds__(256) void gemm_out(const unsigned short* __restrict__ IV,
                                                const unsigned short* __restrict__ Wbf,
                                                const float* __restrict__ W_b,
                                                float* __restrict__ out) {
    const int jt = blockIdx.x, ct = blockIdx.y, b = blockIdx.z;
    const int tid = threadIdx.x;
    const int w = tid >> 6, l = tid & 63;
    const int wr = w >> 1, wc = w & 1;
    const int row_base = ct * 128 + wr * 64;   // c
    const int col_base = jt * 128 + wc * 64;   // j
    const int lr = l & 15, kg = l >> 4;

    f32x4 acc[4][4];
    #pragma unroll
    for (int i = 0; i < 4; ++i)
        #pragma unroll
        for (int jj = 0; jj < 4; ++jj)
            acc[i][jj] = (f32x4){0.f, 0.f, 0.f, 0.f};

    const unsigned short* Ab = IV + (size_t)b * 512 * 1024;

    for (int kk = 0; kk < 1024; kk += 32) {
        bf16x8 af[4], bfm[4];
        #pragma unroll
        for (int i = 0; i < 4; ++i)
            af[i] = *(const bf16x8*)(Ab + (size_t)(row_base + i * 16 + lr) * 1024 + kk + kg * 8);
        #pragma unroll
        for (int i = 0; i < 4; ++i)
            bfm[i] = *(const bf16x8*)(Wbf + (size_t)(col_base + i * 16 + lr) * 1024 + kk + kg * 8);
        #pragma unroll
        for (int mi = 0; mi < 4; ++mi)
            #pragma unroll
            for (int ni = 0; ni < 4; ++ni)
                acc[mi][ni] = __builtin_amdgcn_mfma_f32_16x16x32_bf16(
                    af[mi], bfm[ni], acc[mi][ni], 0, 0, 0);
    }

    #pragma unroll
    for (int mi = 0; mi < 4; ++mi) {
        #pragma unroll
        for (int ni = 0; ni < 4; ++ni) {
            #pragma unroll
            for (int r = 0; r < 4; ++r) {
                int c = row_base + mi * 16 + kg * 4 + r;   // row = (lane>>4)*4 + reg
                int j = col_base + ni * 16 + lr;           // col = lane&15
                out[((size_t)b * 512 + c) * 1024 + j] = acc[mi][ni][r] + W_b[j];
            }
        }
    }
}

extern "C" void kernel_launch(void* const* d_in, const int* in_sizes, int n_in,
                              void* d_out, int out_size, void* d_ws, size_t ws_size,
                              hipStream_t stream) {
    const float* X      = (const float*)d_in[0];
    const float* Wq_w   = (const float*)d_in[1];
    const float* Wq_b   = (const float*)d_in[2];
    const float* Wk_w   = (const float*)d_in[3];
    const float* Wk_b   = (const float*)d_in[4];
    const float* Wkey   = (const float*)d_in[5];
    const float* u      = (const float*)d_in[6];
    // d_in[7] = R : analytically reconstructed, never read
    const float* center = (const float*)d_in[8];
    const float* alpha  = (const float*)d_in[9];
    const float* W_w    = (const float*)d_in[10];
    const float* W_b    = (const float*)d_in[11];
    float* out = (float*)d_out;

    char* ws = (char*)d_ws;
    float*          Qbuf = (float*)ws;                               // 512 KB
    float*          Kbuf = (float*)(ws + (512u << 10));              // 512 KB
    unsigned short* Wbf  = (unsigned short*)(ws + (1024u << 10));    // 2 MB
    unsigned short* IV   = (unsigned short*)(ws + (3072u << 10));    // 8 MB

    conv_w_kernel<<<1024, 256, 0, stream>>>(W_w, Wbf);
    qk_prep<<<1024, 256, 0, stream>>>(X, Wq_w, Wq_b, Wk_w, Wk_b, Qbuf, Kbuf);
    attn_kernel<<<dim3(128, 8), 512, 0, stream>>>(X, Qbuf, Kbuf, u, Wkey, center, alpha, IV);
    gemm_out<<<dim3(8, 4, 8), 256, 0, stream>>>(IV, Wbf, W_b, out);
}

// Round 3
// 215.312 us; speedup vs baseline: 2.1851x; 2.1851x over previous
//
#include <hip/hip_runtime.h>
#include <hip/hip_bf16.h>

#define BS   8
#define TT   1024
#define DIN  64
#define NH   8
#define DOUT 1024

typedef __attribute__((ext_vector_type(8))) short bf16x8;
typedef __attribute__((ext_vector_type(8))) unsigned short u16x8;
typedef __attribute__((ext_vector_type(4))) float f32x4;

__device__ __forceinline__ unsigned short f2bf(float f) {
    unsigned int u = __float_as_uint(f);
    u += 0x7fff + ((u >> 16) & 1);          // RNE
    return (unsigned short)(u >> 16);
}

// ---------------- Kernel 0: W_w (f32) -> bf16 ----------------
__global__ __launch_bounds__(256) void conv_w_kernel(const float* __restrict__ W,
                                                     unsigned short* __restrict__ Wb) {
    int i = blockIdx.x * 256 + threadIdx.x;
    float4 v = ((const float4*)W)[i];
    ushort4 o;
    o.x = f2bf(v.x); o.y = f2bf(v.y); o.z = f2bf(v.z); o.w = f2bf(v.w);
    ((ushort4*)Wb)[i] = o;
}

// ---------------- Kernel 0b: X (f32 [b][l][64]) -> Xt (bf16 [b][64][1024]) ----------------
__global__ __launch_bounds__(256) void xt_prep(const float* __restrict__ X,
                                               unsigned short* __restrict__ Xt) {
    int b = blockIdx.y, l0 = blockIdx.x * 64;
    __shared__ unsigned short S[64][65];
    int tid = threadIdx.x;
    int r = tid >> 4;              // 0..15
    int q4 = (tid & 15) * 4;
    #pragma unroll
    for (int p = 0; p < 4; ++p) {
        int row = p * 16 + r;
        float4 v = *(const float4*)(X + ((size_t)(b * 1024 + l0 + row)) * 64 + q4);
        S[row][q4 + 0] = f2bf(v.x);
        S[row][q4 + 1] = f2bf(v.y);
        S[row][q4 + 2] = f2bf(v.z);
        S[row][q4 + 3] = f2bf(v.w);
    }
    __syncthreads();
    #pragma unroll
    for (int p = 0; p < 4; ++p) {
        int d = p * 16 + r;
        int l = q4;
        ushort4 o;
        o.x = S[l + 0][d]; o.y = S[l + 1][d]; o.z = S[l + 2][d]; o.w = S[l + 3][d];
        *(ushort4*)(Xt + ((size_t)(b * 64 + d)) * 1024 + l0 + l) = o;
    }
}

// ---------------- Kernel 1: q/k projection ----------------
__global__ __launch_bounds__(256) void qk_prep(const float* __restrict__ X,
                                               const float* __restrict__ Wq_w,
                                               const float* __restrict__ Wq_b,
                                               const float* __restrict__ Wk_w,
                                               const float* __restrict__ Wk_b,
                                               float* __restrict__ Q,
                                               float* __restrict__ K) {
    __shared__ float Ws[32][65];
    __shared__ float bs[32];
    __shared__ float Xs[8][64];
    int tid = threadIdx.x;
    for (int i = tid; i < 2048; i += 256) {
        int r = i >> 6, d = i & 63;
        Ws[r][d] = (r < 16) ? Wq_w[r * 64 + d] : Wk_w[(r - 16) * 64 + d];
    }
    if (tid < 32) bs[tid] = (tid < 16) ? Wq_b[tid] : Wk_b[tid - 16];
    int row0 = blockIdx.x * 8;
    for (int i = tid; i < 512; i += 256) {
        int r = i >> 6, d = i & 63;
        Xs[r][d] = X[(size_t)(row0 + r) * 64 + d];
    }
    __syncthreads();
    int r = tid >> 5;
    int j = tid & 31;
    float s = bs[j];
    #pragma unroll
    for (int d = 0; d < 64; ++d) s = fmaf(Xs[r][d], Ws[j][d], s);
    int row = row0 + r;
    if (j < 16) {
        Q[(size_t)row * 16 + j] = s;
    } else {
        int h = (j - 16) >> 1, d2 = (j - 16) & 1;
        int b = row >> 10, l = row & 1023;
        K[(((size_t)(b * 8 + h)) * 1024 + l) * 2 + d2] = s;
    }
}

// ---------------- Kernel 2: fused scores + online softmax + MFMA PV ----------------
// grid (16 t-blocks, 8 h, 8 b), block 256 = 4 waves; wave = 16 t rows.
// D = Xt_frag(16d x 32l) . P_frag(32l x 16t), acc over l. IV bf16 [b][h*64+d][t]
__global__ __launch_bounds__(256) void attn_mfma(const unsigned short* __restrict__ Xt,
                                                 const float* __restrict__ Q,
                                                 const float* __restrict__ K,
                                                 const float* __restrict__ u,
                                                 const float* __restrict__ Wkey,
                                                 const float* __restrict__ center,
                                                 const float* __restrict__ alpha,
                                                 unsigned short* __restrict__ IV) {
    const int h  = blockIdx.y;
    const int bb = blockIdx.z;
    const int tid = threadIdx.x;
    const int w = tid >> 6, lane = tid & 63;
    const int g = lane >> 4, tr = lane & 15;
    const int t0 = blockIdx.x * 64 + w * 16;
    const int t  = t0 + tr;

    __shared__ float Ks[2048];          // K[l][2] for this (b,h)
    {
        const float4* Kg = (const float4*)(K + ((size_t)(bb * 8 + h)) * 2048);
        float4* Ks4 = (float4*)Ks;
        Ks4[tid] = Kg[tid];
        Ks4[tid + 256] = Kg[tid + 256];
    }

    const float L2E = 1.4426950408889634f;
    float2 q  = ((const float2*)Q)[(size_t)(bb * 1024 + t) * 8 + h];
    float2 uu = ((const float2*)u)[t];
    const float al = alpha[0];
    const float a0 = (q.x + uu.x) * L2E;
    const float a1 = (q.y + uu.y) * L2E;
    const float p0 = q.x - al;
    const float p1 = q.y + 2.0f * al * center[h];
    const float c0 = (p0 * Wkey[0] + p1 * Wkey[2]) * L2E;
    const float c1 = (p0 * Wkey[1] + p1 * Wkey[3]) * L2E;
    const float tf = (float)t;

    f32x4 acc[4];
    #pragma unroll
    for (int mi = 0; mi < 4; ++mi) acc[mi] = (f32x4){0.f, 0.f, 0.f, 0.f};
    float mrun = -1e30f, sum = 0.f;

    __syncthreads();

    for (int l0 = 0; l0 < 1024; l0 += 32) {
        const int lb = l0 + g * 8;
        const float4* kp = (const float4*)Ks + (lb >> 1);
        float4 k0 = kp[0], k1 = kp[1], k2 = kp[2], k3 = kp[3];
        float kx[8] = {k0.x, k0.z, k1.x, k1.z, k2.x, k2.z, k3.x, k3.z};
        float ky[8] = {k0.y, k0.w, k1.y, k1.w, k2.y, k2.w, k3.y, k3.w};
        const float dlb = (float)lb - tf;
        float s[8];
        #pragma unroll
        for (int j = 0; j < 8; ++j) {
            float dl = dlb + (float)j;
            s[j] = fmaf(fmaf(c0, dl, c1), dl, fmaf(a0, kx[j], a1 * ky[j]));
        }
        float m8 = fmaxf(fmaxf(fmaxf(s[0], s[1]), fmaxf(s[2], s[3])),
                         fmaxf(fmaxf(s[4], s[5]), fmaxf(s[6], s[7])));
        m8 = fmaxf(m8, __shfl_xor(m8, 16));
        m8 = fmaxf(m8, __shfl_xor(m8, 32));
        float nm = fmaxf(mrun, m8);
        float sc = exp2f(mrun - nm);
        mrun = nm;
        sum *= sc;
        #pragma unroll
        for (int mi = 0; mi < 4; ++mi) {
            acc[mi][0] *= sc; acc[mi][1] *= sc; acc[mi][2] *= sc; acc[mi][3] *= sc;
        }
        float e[8];
        #pragma unroll
        for (int j = 0; j < 8; ++j) e[j] = exp2f(s[j] - mrun);
        sum += ((e[0] + e[1]) + (e[2] + e[3])) + ((e[4] + e[5]) + (e[6] + e[7]));
        union { bf16x8 v; unsigned int wd[4]; } pb;
        #pragma unroll
        for (int jj = 0; jj < 4; ++jj)
            asm("v_cvt_pk_bf16_f32 %0, %1, %2"
                : "=v"(pb.wd[jj]) : "v"(e[2 * jj]), "v"(e[2 * jj + 1]));
        #pragma unroll
        for (int mi = 0; mi < 4; ++mi) {
            bf16x8 af = *(const bf16x8*)(Xt + ((size_t)(bb * 64 + mi * 16 + tr)) * 1024 + lb);
            acc[mi] = __builtin_amdgcn_mfma_f32_16x16x32_bf16(af, pb.v, acc[mi], 0, 0, 0);
        }
    }

    sum += __shfl_xor(sum, 16);
    sum += __shfl_xor(sum, 32);
    const float rinv = 1.0f / sum;
    #pragma unroll
    for (int mi = 0; mi < 4; ++mi) {
        #pragma unroll
        for (int r = 0; r < 4; ++r) {
            int d = mi * 16 + g * 4 + r;
            IV[((size_t)(bb * 512 + h * 64 + d)) * 1024 + t] = f2bf(acc[mi][r] * rinv);
        }
    }
}

// ---------------- Kernel 3: out = IV(bf16) @ W_w^T(bf16) + W_b ----------------
// grid (8 jt, 8 ct, 8 b), block 512 = 8 waves (2 x 4), wave tile 32x32
// c-rows per batch = 512 -> ct in [0,8) x 64 rows.
__global__ __launch_bounds__(512) void gemm_out(const unsigned short* __restrict__ IV,
                                                const unsigned short* __restrict__ Wbf,
                                                const float* __restrict__ W_b,
                                                float* __restrict__ out) {
    const int jt = blockIdx.x, ct = blockIdx.y, b = blockIdx.z;
    const int tid = threadIdx.x;
    const int w = tid >> 6, l = tid & 63;
    const int wr = w >> 2, wc = w & 3;
    const int row_base = ct * 64 + wr * 32;    // c in [0,512)
    const int col_base = jt * 128 + wc * 32;   // j in [0,1024)
    const int lr = l & 15, kg = l >> 4;

    f32x4 acc[2][2];
    #pragma unroll
    for (int i = 0; i < 2; ++i)
        #pragma unroll
        for (int jj = 0; jj < 2; ++jj)
            acc[i][jj] = (f32x4){0.f, 0.f, 0.f, 0.f};

    const unsigned short* Ab = IV + (size_t)b * 512 * 1024;

    for (int kk = 0; kk < 1024; kk += 32) {
        bf16x8 af[2], bfm[2];
        #pragma unroll
        for (int i = 0; i < 2; ++i)
            af[i] = *(const bf16x8*)(Ab + (size_t)(row_base + i * 16 + lr) * 1024 + kk + kg * 8);
        #pragma unroll
        for (int i = 0; i < 2; ++i)
            bfm[i] = *(const bf16x8*)(Wbf + (size_t)(col_base + i * 16 + lr) * 1024 + kk + kg * 8);
        #pragma unroll
        for (int mi = 0; mi < 2; ++mi)
            #pragma unroll
            for (int ni = 0; ni < 2; ++ni)
                acc[mi][ni] = __builtin_amdgcn_mfma_f32_16x16x32_bf16(
                    af[mi], bfm[ni], acc[mi][ni], 0, 0, 0);
    }

    #pragma unroll
    for (int mi = 0; mi < 2; ++mi) {
        #pragma unroll
        for (int ni = 0; ni < 2; ++ni) {
            #pragma unroll
            for (int r = 0; r < 4; ++r) {
                int c = row_base + mi * 16 + kg * 4 + r;
                int j = col_base + ni * 16 + lr;
                out[((size_t)b * 512 + c) * 1024 + j] = acc[mi][ni][r] + W_b[j];
            }
        }
    }
}

extern "C" void kernel_launch(void* const* d_in, const int* in_sizes, int n_in,
                              void* d_out, int out_size, void* d_ws, size_t ws_size,
                              hipStream_t stream) {
    const float* X      = (const float*)d_in[0];
    const float* Wq_w   = (const float*)d_in[1];
    const float* Wq_b   = (const float*)d_in[2];
    const float* Wk_w   = (const float*)d_in[3];
    const float* Wk_b   = (const float*)d_in[4];
    const float* Wkey   = (const float*)d_in[5];
    const float* u      = (const float*)d_in[6];
    // d_in[7] = R : analytically reconstructed, never read
    const float* center = (const float*)d_in[8];
    const float* alpha  = (const float*)d_in[9];
    const float* W_w    = (const float*)d_in[10];
    const float* W_b    = (const float*)d_in[11];
    float* out = (float*)d_out;

    // Workspace (peak 10 MB):
    //   region A (0..2 MB): Xt(1MB) | Q(512K) | K(512K)  -- dead after attn_mfma
    //   region A reused:    Wbf(2MB)                      -- written after attn_mfma
    //   region B (2..10 MB): IV (8MB)
    char* ws = (char*)d_ws;
    unsigned short* Xt   = (unsigned short*)ws;                      // 1 MB
    float*          Qbuf = (float*)(ws + (1024u << 10));             // 512 KB
    float*          Kbuf = (float*)(ws + (1536u << 10));             // 512 KB
    unsigned short* Wbf  = (unsigned short*)ws;                      // 2 MB (aliases Xt/Q/K)
    unsigned short* IV   = (unsigned short*)(ws + (2048u << 10));    // 8 MB

    xt_prep<<<dim3(16, 8), 256, 0, stream>>>(X, Xt);
    qk_prep<<<1024, 256, 0, stream>>>(X, Wq_w, Wq_b, Wk_w, Wk_b, Qbuf, Kbuf);
    attn_mfma<<<dim3(16, 8, 8), 256, 0, stream>>>(Xt, Qbuf, Kbuf, u, Wkey, center, alpha, IV);
    conv_w_kernel<<<1024, 256, 0, stream>>>(W_w, Wbf);   // after attn: Wbf aliases Xt/Q/K
    gemm_out<<<dim3(8, 8, 8), 512, 0, stream>>>(IV, Wbf, W_b, out);
}

// Round 4
// 178.019 us; speedup vs baseline: 2.6428x; 1.2095x over previous
//
#include <hip/hip_runtime.h>
#include <hip/hip_bf16.h>

#define BS   8
#define TT   1024
#define DIN  64
#define NH   8
#define DOUT 1024

typedef __attribute__((ext_vector_type(8))) short bf16x8;
typedef __attribute__((ext_vector_type(8))) unsigned short u16x8;
typedef __attribute__((ext_vector_type(4))) float f32x4;

typedef __attribute__((address_space(3))) unsigned int lds_u32;
typedef const __attribute__((address_space(1))) unsigned int glb_u32;

__device__ __forceinline__ unsigned short f2bf(float f) {
    unsigned int u = __float_as_uint(f);
    u += 0x7fff + ((u >> 16) & 1);          // RNE
    return (unsigned short)(u >> 16);
}

// ---------------- Kernel 0: W_w (f32) -> bf16 ----------------
__global__ __launch_bounds__(256) void conv_w_kernel(const float* __restrict__ W,
                                                     unsigned short* __restrict__ Wb) {
    int i = blockIdx.x * 256 + threadIdx.x;
    float4 v = ((const float4*)W)[i];
    ushort4 o;
    o.x = f2bf(v.x); o.y = f2bf(v.y); o.z = f2bf(v.z); o.w = f2bf(v.w);
    ((ushort4*)Wb)[i] = o;
}

// ---------------- Kernel 0b: X (f32 [b][l][64]) -> Xt (bf16 [b][64][1024]) ----------------
__global__ __launch_bounds__(256) void xt_prep(const float* __restrict__ X,
                                               unsigned short* __restrict__ Xt) {
    int b = blockIdx.y, l0 = blockIdx.x * 64;
    __shared__ unsigned short S[64][65];
    int tid = threadIdx.x;
    int r = tid >> 4;              // 0..15
    int q4 = (tid & 15) * 4;
    #pragma unroll
    for (int p = 0; p < 4; ++p) {
        int row = p * 16 + r;
        float4 v = *(const float4*)(X + ((size_t)(b * 1024 + l0 + row)) * 64 + q4);
        S[row][q4 + 0] = f2bf(v.x);
        S[row][q4 + 1] = f2bf(v.y);
        S[row][q4 + 2] = f2bf(v.z);
        S[row][q4 + 3] = f2bf(v.w);
    }
    __syncthreads();
    #pragma unroll
    for (int p = 0; p < 4; ++p) {
        int d = p * 16 + r;
        int l = q4;
        ushort4 o;
        o.x = S[l + 0][d]; o.y = S[l + 1][d]; o.z = S[l + 2][d]; o.w = S[l + 3][d];
        *(ushort4*)(Xt + ((size_t)(b * 64 + d)) * 1024 + l0 + l) = o;
    }
}

// ---------------- Kernel 1: q/k projection ----------------
__global__ __launch_bounds__(256) void qk_prep(const float* __restrict__ X,
                                               const float* __restrict__ Wq_w,
                                               const float* __restrict__ Wq_b,
                                               const float* __restrict__ Wk_w,
                                               const float* __restrict__ Wk_b,
                                               float* __restrict__ Q,
                                               float* __restrict__ K) {
    __shared__ float Ws[32][65];
    __shared__ float bs[32];
    __shared__ float Xs[8][64];
    int tid = threadIdx.x;
    for (int i = tid; i < 2048; i += 256) {
        int r = i >> 6, d = i & 63;
        Ws[r][d] = (r < 16) ? Wq_w[r * 64 + d] : Wk_w[(r - 16) * 64 + d];
    }
    if (tid < 32) bs[tid] = (tid < 16) ? Wq_b[tid] : Wk_b[tid - 16];
    int row0 = blockIdx.x * 8;
    for (int i = tid; i < 512; i += 256) {
        int r = i >> 6, d = i & 63;
        Xs[r][d] = X[(size_t)(row0 + r) * 64 + d];
    }
    __syncthreads();
    int r = tid >> 5;
    int j = tid & 31;
    float s = bs[j];
    #pragma unroll
    for (int d = 0; d < 64; ++d) s = fmaf(Xs[r][d], Ws[j][d], s);
    int row = row0 + r;
    if (j < 16) {
        Q[(size_t)row * 16 + j] = s;
    } else {
        int h = (j - 16) >> 1, d2 = (j - 16) & 1;
        int b = row >> 10, l = row & 1023;
        K[(((size_t)(b * 8 + h)) * 1024 + l) * 2 + d2] = s;
    }
}

// ---------------- Kernel 1b: per-(b,h) K extrema for analytic max bound ----------------
__global__ __launch_bounds__(256) void kmax_prep(const float* __restrict__ K,
                                                 float4* __restrict__ KM) {
    int bh = blockIdx.x;                         // 0..63
    const float2* K2 = (const float2*)(K + (size_t)bh * 2048);
    int tid = threadIdx.x, w = tid >> 6, lane = tid & 63;
    float mxp = -1e30f, mxn = 1e30f, myp = -1e30f, myn = 1e30f;
    for (int l = tid; l < 1024; l += 256) {
        float2 kk = K2[l];
        mxp = fmaxf(mxp, kk.x); mxn = fminf(mxn, kk.x);
        myp = fmaxf(myp, kk.y); myn = fminf(myn, kk.y);
    }
    for (int off = 32; off; off >>= 1) {
        mxp = fmaxf(mxp, __shfl_xor(mxp, off));
        mxn = fminf(mxn, __shfl_xor(mxn, off));
        myp = fmaxf(myp, __shfl_xor(myp, off));
        myn = fminf(myn, __shfl_xor(myn, off));
    }
    __shared__ float red[4][4];
    if (lane == 0) { red[w][0] = mxp; red[w][1] = mxn; red[w][2] = myp; red[w][3] = myn; }
    __syncthreads();
    if (tid == 0) {
        float a = fmaxf(fmaxf(red[0][0], red[1][0]), fmaxf(red[2][0], red[3][0]));
        float b = fminf(fminf(red[0][1], red[1][1]), fminf(red[2][1], red[3][1]));
        float c = fmaxf(fmaxf(red[0][2], red[1][2]), fmaxf(red[2][2], red[3][2]));
        float d = fminf(fminf(red[0][3], red[1][3]), fminf(red[2][3], red[3][3]));
        KM[bh] = make_float4(a, b, c, d);
    }
}

// ---------------- Kernel 2: scores + single-pass softmax (analytic max) + MFMA PV ----------------
// grid (16 t-blocks, 8 h, 8 b), block 256 = 4 waves; wave = 16 t rows.
// D = Xt_frag(16d x 32l) . P_frag(32l x 16t), acc over l. IV bf16 [b][h*64+d][t]
__global__ __launch_bounds__(256) void attn_mfma(const unsigned short* __restrict__ Xt,
                                                 const float* __restrict__ Q,
                                                 const float* __restrict__ K,
                                                 const float* __restrict__ u,
                                                 const float* __restrict__ Wkey,
                                                 const float* __restrict__ center,
                                                 const float* __restrict__ alpha,
                                                 const float4* __restrict__ KM,
                                                 unsigned short* __restrict__ IV) {
    const int h  = blockIdx.y;
    const int bb = blockIdx.z;
    const int tid = threadIdx.x;
    const int w = tid >> 6, lane = tid & 63;
    const int g = lane >> 4, tr = lane & 15;
    const int t = blockIdx.x * 64 + w * 16 + tr;

    __shared__ float Ks[2048];          // K[l][2] for this (b,h)
    {
        const float4* Kg = (const float4*)(K + ((size_t)(bb * 8 + h)) * 2048);
        float4* Ks4 = (float4*)Ks;
        Ks4[tid] = Kg[tid];
        Ks4[tid + 256] = Kg[tid + 256];
    }

    const float L2E = 1.4426950408889634f;
    float2 q  = ((const float2*)Q)[(size_t)(bb * 1024 + t) * 8 + h];
    float2 uu = ((const float2*)u)[t];
    const float al = alpha[0];
    const float a0 = (q.x + uu.x) * L2E;
    const float a1 = (q.y + uu.y) * L2E;
    const float p0 = q.x - al;
    const float p1 = q.y + 2.0f * al * center[h];
    const float c0 = (p0 * Wkey[0] + p1 * Wkey[2]) * L2E;
    const float c1 = (p0 * Wkey[1] + p1 * Wkey[3]) * L2E;
    const float tf = (float)t;

    // analytic upper bound on max score: quad part (closed form) + qk part (K extrema)
    float4 km = KM[bb * 8 + h];
    const float qb = fmaxf(a0 * km.x, a0 * km.y) + fmaxf(a1 * km.z, a1 * km.w);
    const float dlo = -tf, dhi = 1023.0f - tf;
    float qm = fmaxf(fmaf(fmaf(c0, dlo, c1), dlo, 0.0f),
                     fmaf(fmaf(c0, dhi, c1), dhi, 0.0f));
    if (c0 < 0.0f) {
        float dstar = -c1 / (2.0f * c0);
        if (dstar > dlo && dstar < dhi) qm = -c1 * c1 / (4.0f * c0);
    }
    const float negm = -(qm + qb);

    f32x4 acc[4];
    #pragma unroll
    for (int mi = 0; mi < 4; ++mi) acc[mi] = (f32x4){0.f, 0.f, 0.f, 0.f};
    float sum = 0.f;

    __syncthreads();

    for (int l0 = 0; l0 < 1024; l0 += 32) {
        const int lb = l0 + g * 8;
        const float4* kp = (const float4*)Ks + (lb >> 1);
        float4 k0 = kp[0], k1 = kp[1], k2 = kp[2], k3 = kp[3];
        float kx[8] = {k0.x, k0.z, k1.x, k1.z, k2.x, k2.z, k3.x, k3.z};
        float ky[8] = {k0.y, k0.w, k1.y, k1.w, k2.y, k2.w, k3.y, k3.w};
        const float dlb = (float)lb - tf;
        float e[8];
        #pragma unroll
        for (int j = 0; j < 8; ++j) {
            float dl = dlb + (float)j;
            float base = fmaf(a0, kx[j], fmaf(a1, ky[j], negm));
            e[j] = exp2f(fmaf(fmaf(c0, dl, c1), dl, base));
        }
        sum += ((e[0] + e[1]) + (e[2] + e[3])) + ((e[4] + e[5]) + (e[6] + e[7]));
        union { bf16x8 v; unsigned int wd[4]; } pb;
        #pragma unroll
        for (int jj = 0; jj < 4; ++jj)
            asm("v_cvt_pk_bf16_f32 %0, %1, %2"
                : "=v"(pb.wd[jj]) : "v"(e[2 * jj]), "v"(e[2 * jj + 1]));
        #pragma unroll
        for (int mi = 0; mi < 4; ++mi) {
            bf16x8 af = *(const bf16x8*)(Xt + ((size_t)(bb * 64 + mi * 16 + tr)) * 1024 + lb);
            acc[mi] = __builtin_amdgcn_mfma_f32_16x16x32_bf16(af, pb.v, acc[mi], 0, 0, 0);
        }
    }

    sum += __shfl_xor(sum, 16);
    sum += __shfl_xor(sum, 32);
    const float rinv = 1.0f / sum;
    #pragma unroll
    for (int mi = 0; mi < 4; ++mi) {
        #pragma unroll
        for (int r = 0; r < 4; ++r) {
            int d = mi * 16 + g * 4 + r;
            IV[((size_t)(bb * 512 + h * 64 + d)) * 1024 + t] = f2bf(acc[mi][r] * rinv);
        }
    }
}

// ---------------- Kernel 3: out = IV @ W_w^T + W_b, fused M=4096, LDS-staged ----------------
// Tile 64(m) x 128(n), BK=32. grid (8 jt, 64 mt), block 256 = 4 waves, wave = 64x32.
__global__ __launch_bounds__(256) void gemm_out(const unsigned short* __restrict__ IV,
                                                const unsigned short* __restrict__ Wbf,
                                                const float* __restrict__ W_b,
                                                float* __restrict__ out) {
    const int jt = blockIdx.x;      // 0..7  (128 cols)
    const int mt = blockIdx.y;      // 0..63 (64 rows of fused 4096)
    const int tid = threadIdx.x;
    const int wc = tid >> 6;        // wave -> 32-col slice
    const int lane = tid & 63, lr = lane & 15, kg = lane >> 4;

    __shared__ unsigned short As[64 * 32];    // 4 KB
    __shared__ unsigned short Bs[128 * 32];   // 8 KB

    const int srow = tid >> 2;                 // 0..63
    const int skoff = (tid & 3) * 8;           // 0,8,16,24
    const unsigned short* Ag  = IV  + (size_t)(mt * 64 + srow) * 1024 + skoff;
    const unsigned short* Bg0 = Wbf + (size_t)(jt * 128 + srow) * 1024 + skoff;
    const unsigned short* Bg1 = Bg0 + (size_t)64 * 1024;
    unsigned short* Asl  = As + tid * 8;
    unsigned short* Bsl0 = Bs + tid * 8;
    unsigned short* Bsl1 = Bs + 2048 + tid * 8;

    f32x4 acc[4][2];
    #pragma unroll
    for (int mi = 0; mi < 4; ++mi)
        #pragma unroll
        for (int ni = 0; ni < 2; ++ni)
            acc[mi][ni] = (f32x4){0.f, 0.f, 0.f, 0.f};

    for (int kk = 0; kk < 1024; kk += 32) {
        __syncthreads();
        __builtin_amdgcn_global_load_lds((glb_u32*)(Ag  + kk), (lds_u32*)Asl,  16, 0, 0);
        __builtin_amdgcn_global_load_lds((glb_u32*)(Bg0 + kk), (lds_u32*)Bsl0, 16, 0, 0);
        __builtin_amdgcn_global_load_lds((glb_u32*)(Bg1 + kk), (lds_u32*)Bsl1, 16, 0, 0);
        __syncthreads();
        bf16x8 af[4], bfr[2];
        #pragma unroll
        for (int mi = 0; mi < 4; ++mi)
            af[mi] = *(const bf16x8*)(As + (mi * 16 + lr) * 32 + kg * 8);
        #pragma unroll
        for (int ni = 0; ni < 2; ++ni)
            bfr[ni] = *(const bf16x8*)(Bs + (wc * 32 + ni * 16 + lr) * 32 + kg * 8);
        #pragma unroll
        for (int mi = 0; mi < 4; ++mi)
            #pragma unroll
            for (int ni = 0; ni < 2; ++ni)
                acc[mi][ni] = __builtin_amdgcn_mfma_f32_16x16x32_bf16(
                    af[mi], bfr[ni], acc[mi][ni], 0, 0, 0);
    }

    #pragma unroll
    for (int mi = 0; mi < 4; ++mi) {
        #pragma unroll
        for (int ni = 0; ni < 2; ++ni) {
            #pragma unroll
            for (int r = 0; r < 4; ++r) {
                int rowf = mt * 64 + mi * 16 + kg * 4 + r;    // fused row (b*512+c)
                int j = jt * 128 + wc * 32 + ni * 16 + lr;
                out[(size_t)rowf * 1024 + j] = acc[mi][ni][r] + W_b[j];
            }
        }
    }
}

extern "C" void kernel_launch(void* const* d_in, const int* in_sizes, int n_in,
                              void* d_out, int out_size, void* d_ws, size_t ws_size,
                              hipStream_t stream) {
    const float* X      = (const float*)d_in[0];
    const float* Wq_w   = (const float*)d_in[1];
    const float* Wq_b   = (const float*)d_in[2];
    const float* Wk_w   = (const float*)d_in[3];
    const float* Wk_b   = (const float*)d_in[4];
    const float* Wkey   = (const float*)d_in[5];
    const float* u      = (const float*)d_in[6];
    // d_in[7] = R : analytically reconstructed, never read
    const float* center = (const float*)d_in[8];
    const float* alpha  = (const float*)d_in[9];
    const float* W_w    = (const float*)d_in[10];
    const float* W_b    = (const float*)d_in[11];
    float* out = (float*)d_out;

    // Workspace (proven >= 12.25 MB from round-1 pass):
    //   0..2 MB  : Xt(1MB) | Q(512K) | K(512K)  -- dead after attn; Wbf(2MB) aliases after
    //   2..10 MB : IV (8MB)
    //   10 MB    : KM (1KB)
    char* ws = (char*)d_ws;
    unsigned short* Xt   = (unsigned short*)ws;                      // 1 MB
    float*          Qbuf = (float*)(ws + (1024u << 10));             // 512 KB
    float*          Kbuf = (float*)(ws + (1536u << 10));             // 512 KB
    unsigned short* Wbf  = (unsigned short*)ws;                      // 2 MB (aliases Xt/Q/K)
    unsigned short* IV   = (unsigned short*)(ws + (2048u << 10));    // 8 MB
    float4*         KM   = (float4*)(ws + (10240u << 10));           // 1 KB

    xt_prep<<<dim3(16, 8), 256, 0, stream>>>(X, Xt);
    qk_prep<<<1024, 256, 0, stream>>>(X, Wq_w, Wq_b, Wk_w, Wk_b, Qbuf, Kbuf);
    kmax_prep<<<64, 256, 0, stream>>>(Kbuf, KM);
    attn_mfma<<<dim3(16, 8, 8), 256, 0, stream>>>(Xt, Qbuf, Kbuf, u, Wkey, center, alpha, KM, IV);
    conv_w_kernel<<<1024, 256, 0, stream>>>(W_w, Wbf);   // after attn: Wbf aliases Xt/Q/K
    gemm_out<<<dim3(8, 64), 256, 0, stream>>>(IV, Wbf, W_b, out);
}

// Round 6
// 151.731 us; speedup vs baseline: 3.1007x; 1.1733x over previous
//
#include <hip/hip_runtime.h>
#include <hip/hip_bf16.h>

#define BS   8
#define TT   1024
#define DIN  64
#define NH   8
#define DOUT 1024

typedef __attribute__((ext_vector_type(8))) short bf16x8;
typedef __attribute__((ext_vector_type(8))) unsigned short u16x8;
typedef __attribute__((ext_vector_type(4))) float f32x4;

typedef __attribute__((address_space(3))) unsigned int lds_u32;
typedef const __attribute__((address_space(1))) unsigned int glb_u32;

__device__ __forceinline__ unsigned short f2bf(float f) {
    unsigned int u = __float_as_uint(f);
    u += 0x7fff + ((u >> 16) & 1);          // RNE
    return (unsigned short)(u >> 16);
}

// ---------------- Kernel A: fused prep ----------------
// blocks 0..1023   : qk projection (8 rows each)
// blocks 1024..1151: X -> XtP packed-fragment bf16 transpose
// blocks 1152..2175: W_w -> bf16
__global__ __launch_bounds__(256) void prep_fused(const float* __restrict__ X,
                                                  const float* __restrict__ Wq_w,
                                                  const float* __restrict__ Wq_b,
                                                  const float* __restrict__ Wk_w,
                                                  const float* __restrict__ Wk_b,
                                                  const float* __restrict__ W_w,
                                                  float* __restrict__ Q,
                                                  float* __restrict__ K,
                                                  unsigned short* __restrict__ XtP,
                                                  unsigned short* __restrict__ Wbf) {
    __shared__ float Ws[32][65];
    __shared__ float bsm[32];
    __shared__ float Xs[8][64];
    __shared__ unsigned short S[64][68];

    const int bid = blockIdx.x, tid = threadIdx.x;

    if (bid < 1024) {
        // ---- qk projection ----
        for (int i = tid; i < 2048; i += 256) {
            int r = i >> 6, d = i & 63;
            Ws[r][d] = (r < 16) ? Wq_w[r * 64 + d] : Wk_w[(r - 16) * 64 + d];
        }
        if (tid < 32) bsm[tid] = (tid < 16) ? Wq_b[tid] : Wk_b[tid - 16];
        int row0 = bid * 8;
        for (int i = tid; i < 512; i += 256) {
            int r = i >> 6, d = i & 63;
            Xs[r][d] = X[(size_t)(row0 + r) * 64 + d];
        }
        __syncthreads();
        int r = tid >> 5;
        int j = tid & 31;
        float s = bsm[j];
        #pragma unroll
        for (int d = 0; d < 64; ++d) s = fmaf(Xs[r][d], Ws[j][d], s);
        int row = row0 + r;
        if (j < 16) {
            Q[(size_t)row * 16 + j] = s;
        } else {
            int h = (j - 16) >> 1, d2 = (j - 16) & 1;
            int b = row >> 10, l = row & 1023;
            K[(((size_t)(b * 8 + h)) * 1024 + l) * 2 + d2] = s;
        }
    } else if (bid < 1152) {
        // ---- XtP pack: chunk ((bb*32+lblk)*4+mi)*64+lane holds
        //      X[bb][lblk*32 + (lane>>4)*8 + j][mi*16 + (lane&15)], j=0..7
        int idx = bid - 1024;            // 0..127
        int bb = idx >> 4, lc = idx & 15;
        int l0 = lc * 64;
        int r = tid >> 4;                // 0..15
        int q4 = (tid & 15) * 4;
        #pragma unroll
        for (int p = 0; p < 4; ++p) {
            int row = p * 16 + r;
            float4 v = *(const float4*)(X + ((size_t)(bb * 1024 + l0 + row)) * 64 + q4);
            S[row][q4 + 0] = f2bf(v.x);
            S[row][q4 + 1] = f2bf(v.y);
            S[row][q4 + 2] = f2bf(v.z);
            S[row][q4 + 3] = f2bf(v.w);
        }
        __syncthreads();
        #pragma unroll
        for (int it = 0; it < 2; ++it) {
            int chunk = it * 256 + tid;
            int lane = chunk & 63, mi = (chunk >> 6) & 3, lbr = chunk >> 8;
            int g = lane >> 4, tr = lane & 15;
            int d = mi * 16 + tr;
            int ls = lbr * 32 + g * 8;
            u16x8 o;
            #pragma unroll
            for (int j = 0; j < 8; ++j) o[j] = S[ls + j][d];
            *(u16x8*)(XtP + (size_t)((((bb * 32 + lc * 2 + lbr) * 4 + mi) * 64 + lane)) * 8) = o;
        }
    } else {
        // ---- W_w -> bf16 ----
        int i = (bid - 1152) * 256 + tid;
        float4 v = ((const float4*)W_w)[i];
        ushort4 o;
        o.x = f2bf(v.x); o.y = f2bf(v.y); o.z = f2bf(v.z); o.w = f2bf(v.w);
        ((ushort4*)Wbf)[i] = o;
    }
}

// ---------------- Kernel B: scores + analytic-max softmax + MFMA PV ----------------
// grid (32 t-blocks, 8 h, 8 b), block 256 = 4 waves = 2 t-subtiles x 2 l-halves.
// Wave pair (tsub, lhalf=0/1) each does 512 l's; partials combined via LDS
// (valid because the softmax max-bound is analytic and shared).
__global__ __launch_bounds__(256, 8) void attn_mfma(const unsigned short* __restrict__ XtP,
                                                    const float* __restrict__ Q,
                                                    const float* __restrict__ K,
                                                    const float* __restrict__ u,
                                                    const float* __restrict__ Wkey,
                                                    const float* __restrict__ center,
                                                    const float* __restrict__ alpha,
                                                    unsigned short* __restrict__ IV) {
    const int h  = blockIdx.y;
    const int bb = blockIdx.z;
    const int tid = threadIdx.x;
    const int w = tid >> 6, lane = tid & 63;
    const int g = lane >> 4, tr = lane & 15;
    const int tsub = w & 1, lhalf = w >> 1;
    const int t = blockIdx.x * 32 + tsub * 16 + tr;

    __shared__ float SH[2176];          // Ks[2048] then reused as C[2][64][17]
    __shared__ float red[4][4];

    {   // stage K[l][2] for this (b,h)
        const float4* Kg = (const float4*)(K + ((size_t)(bb * 8 + h)) * 2048);
        float4* Ks4 = (float4*)SH;
        Ks4[tid] = Kg[tid];
        Ks4[tid + 256] = Kg[tid + 256];
    }
    __syncthreads();

    // inline K extrema (block-wide)
    float mxp = -1e30f, mxn = 1e30f, myp = -1e30f, myn = 1e30f;
    {
        const float2* K2 = (const float2*)SH;
        #pragma unroll
        for (int i = 0; i < 4; ++i) {
            float2 kk = K2[tid + i * 256];
            mxp = fmaxf(mxp, kk.x); mxn = fminf(mxn, kk.x);
            myp = fmaxf(myp, kk.y); myn = fminf(myn, kk.y);
        }
        #pragma unroll
        for (int off = 32; off; off >>= 1) {
            mxp = fmaxf(mxp, __shfl_xor(mxp, off)); mxn = fminf(mxn, __shfl_xor(mxn, off));
            myp = fmaxf(myp, __shfl_xor(myp, off)); myn = fminf(myn, __shfl_xor(myn, off));
        }
        if (lane == 0) { red[w][0] = mxp; red[w][1] = mxn; red[w][2] = myp; red[w][3] = myn; }
    }
    __syncthreads();
    mxp = fmaxf(fmaxf(red[0][0], red[1][0]), fmaxf(red[2][0], red[3][0]));
    mxn = fminf(fminf(red[0][1], red[1][1]), fminf(red[2][1], red[3][1]));
    myp = fmaxf(fmaxf(red[0][2], red[1][2]), fmaxf(red[2][2], red[3][2]));
    myn = fminf(fminf(red[0][3], red[1][3]), fminf(red[2][3], red[3][3]));

    const float L2E = 1.4426950408889634f;
    float2 q  = ((const float2*)Q)[(size_t)(bb * 1024 + t) * 8 + h];
    float2 uu = ((const float2*)u)[t];
    const float al = alpha[0];
    const float a0 = (q.x + uu.x) * L2E;
    const float a1 = (q.y + uu.y) * L2E;
    const float p0 = q.x - al;
    const float p1 = q.y + 2.0f * al * center[h];
    const float c0 = (p0 * Wkey[0] + p1 * Wkey[2]) * L2E;
    const float c1 = (p0 * Wkey[1] + p1 * Wkey[3]) * L2E;
    const float tf = (float)t;

    // analytic upper bound on max score
    const float qb = fmaxf(a0 * mxp, a0 * mxn) + fmaxf(a1 * myp, a1 * myn);
    const float dlo = -tf, dhi = 1023.0f - tf;
    float qm = fmaxf(fmaf(fmaf(c0, dlo, c1), dlo, 0.0f),
                     fmaf(fmaf(c0, dhi, c1), dhi, 0.0f));
    if (c0 < 0.0f) {
        float dstar = -c1 / (2.0f * c0);
        if (dstar > dlo && dstar < dhi) qm = -c1 * c1 / (4.0f * c0);
    }
    const float negm = -(qm + qb);

    f32x4 acc[4];
    #pragma unroll
    for (int mi = 0; mi < 4; ++mi) acc[mi] = (f32x4){0.f, 0.f, 0.f, 0.f};
    float sum = 0.f;

    const bf16x8* XtPv = (const bf16x8*)XtP;
    const size_t xbase = ((size_t)(bb * 32 + lhalf * 16) * 4) * 64 + lane;

    for (int it = 0; it < 16; ++it) {
        const int l0 = lhalf * 512 + it * 32;
        const int lb = l0 + g * 8;
        const float4* kp = (const float4*)SH + (lb >> 1);   // {x0,y0,x1,y1} pairs
        const float dlb = (float)lb - tf;
        union { bf16x8 v; unsigned int wd[4]; } pb;
        #pragma unroll
        for (int jj = 0; jj < 4; ++jj) {
            float4 kv = kp[jj];
            float dl0 = dlb + (float)(2 * jj);
            float dl1 = dl0 + 1.0f;
            float e0 = exp2f(fmaf(fmaf(c0, dl0, c1), dl0, fmaf(a0, kv.x, fmaf(a1, kv.y, negm))));
            float e1 = exp2f(fmaf(fmaf(c0, dl1, c1), dl1, fmaf(a0, kv.z, fmaf(a1, kv.w, negm))));
            sum += e0 + e1;
            asm("v_cvt_pk_bf16_f32 %0, %1, %2" : "=v"(pb.wd[jj]) : "v"(e0), "v"(e1));
        }
        #pragma unroll
        for (int mi = 0; mi < 4; ++mi)
            acc[mi] = __builtin_amdgcn_mfma_f32_16x16x32_bf16(
                XtPv[xbase + (size_t)it * 256 + mi * 64], pb.v, acc[mi], 0, 0, 0);
    }

    sum += __shfl_xor(sum, 16);
    sum += __shfl_xor(sum, 32);

    __syncthreads();                     // everyone done reading Ks
    if (lhalf == 1) {
        float* cp = SH + (tsub * 64 + lane) * 17;
        #pragma unroll
        for (int mi = 0; mi < 4; ++mi)
            #pragma unroll
            for (int r = 0; r < 4; ++r) cp[mi * 4 + r] = acc[mi][r];
        cp[16] = sum;
    }
    __syncthreads();
    if (lhalf == 0) {
        const float* cp = SH + (tsub * 64 + lane) * 17;
        #pragma unroll
        for (int mi = 0; mi < 4; ++mi)
            #pragma unroll
            for (int r = 0; r < 4; ++r) acc[mi][r] += cp[mi * 4 + r];
        sum += cp[16];
        const float rinv = 1.0f / sum;
        #pragma unroll
        for (int mi = 0; mi < 4; ++mi) {
            #pragma unroll
            for (int r = 0; r < 4; ++r) {
                int d = mi * 16 + g * 4 + r;
                IV[((size_t)(bb * 512 + h * 64 + d)) * 1024 + t] = f2bf(acc[mi][r] * rinv);
            }
        }
    }
}

// ---------------- Kernel C: out = IV @ W_w^T + W_b ----------------
// Fused M=4096. 128x128 tile, BK=32, 2-phase LDS double-buffer via global_load_lds,
// XOR slot swizzle (slot = kg ^ ((row>>1)&3)) for conflict-minimal ds_read_b128.
// grid (8 jt, 32 mt), block 256 = 4 waves (2x2), wave tile 64x64.
__global__ __launch_bounds__(256) void gemm_out(const unsigned short* __restrict__ IV,
                                                const unsigned short* __restrict__ Wbf,
                                                const float* __restrict__ W_b,
                                                float* __restrict__ out) {
    const int jt = blockIdx.x;      // 0..7
    const int mt = blockIdx.y;      // 0..31
    const int tid = threadIdx.x;
    const int w = tid >> 6, lane = tid & 63;
    const int lr = lane & 15, kg = lane >> 4;
    const int wr = w >> 1, wc = w & 1;

    __shared__ unsigned short As[2][128 * 32];
    __shared__ unsigned short Bs[2][128 * 32];

    // staging: thread covers chunks tid and tid+256; chunk c -> row=c>>2, phys slot=c&3
    const int r0 = tid >> 2, s0 = tid & 3;
    const int kg0 = s0 ^ ((r0 >> 1) & 3);
    const int kg1 = s0 ^ (((r0 + 64) >> 1) & 3);
    const unsigned short* Ag0 = IV  + (size_t)(mt * 128 + r0) * 1024 + kg0 * 8;
    const unsigned short* Ag1 = IV  + (size_t)(mt * 128 + r0 + 64) * 1024 + kg1 * 8;
    const unsigned short* Bg0 = Wbf + (size_t)(jt * 128 + r0) * 1024 + kg0 * 8;
    const unsigned short* Bg1 = Wbf + (size_t)(jt * 128 + r0 + 64) * 1024 + kg1 * 8;

#define STAGE(bufi, kk) do {                                                                   \
    __builtin_amdgcn_global_load_lds((glb_u32*)(Ag0 + (kk)), (lds_u32*)(&As[bufi][tid * 8]), 16, 0, 0);          \
    __builtin_amdgcn_global_load_lds((glb_u32*)(Ag1 + (kk)), (lds_u32*)(&As[bufi][(tid + 256) * 8]), 16, 0, 0);  \
    __builtin_amdgcn_global_load_lds((glb_u32*)(Bg0 + (kk)), (lds_u32*)(&Bs[bufi][tid * 8]), 16, 0, 0);          \
    __builtin_amdgcn_global_load_lds((glb_u32*)(Bg1 + (kk)), (lds_u32*)(&Bs[bufi][(tid + 256) * 8]), 16, 0, 0);  \
} while (0)

    f32x4 acc[4][4];
    #pragma unroll
    for (int mi = 0; mi < 4; ++mi)
        #pragma unroll
        for (int ni = 0; ni < 4; ++ni)
            acc[mi][ni] = (f32x4){0.f, 0.f, 0.f, 0.f};

    STAGE(0, 0);
    asm volatile("s_waitcnt vmcnt(0)");
    __syncthreads();

    const int slot = kg ^ ((lr >> 1) & 3);        // same involution as the write side
    int cur = 0;
    for (int kt = 0; kt < 32; ++kt) {
        if (kt < 31) STAGE(cur ^ 1, (kt + 1) * 32);
        bf16x8 af[4], bfr[4];
        #pragma unroll
        for (int mi = 0; mi < 4; ++mi) {
            int row = wr * 64 + mi * 16 + lr;
            af[mi] = *(const bf16x8*)(&As[cur][row * 32 + slot * 8]);
        }
        #pragma unroll
        for (int ni = 0; ni < 4; ++ni) {
            int row = wc * 64 + ni * 16 + lr;
            bfr[ni] = *(const bf16x8*)(&Bs[cur][row * 32 + slot * 8]);
        }
        #pragma unroll
        for (int mi = 0; mi < 4; ++mi)
            #pragma unroll
            for (int ni = 0; ni < 4; ++ni)
                acc[mi][ni] = __builtin_amdgcn_mfma_f32_16x16x32_bf16(
                    af[mi], bfr[ni], acc[mi][ni], 0, 0, 0);
        asm volatile("s_waitcnt vmcnt(0)");
        __syncthreads();
        cur ^= 1;
    }
#undef STAGE

    float wb[4];
    #pragma unroll
    for (int ni = 0; ni < 4; ++ni) wb[ni] = W_b[jt * 128 + wc * 64 + ni * 16 + lr];

    #pragma unroll
    for (int mi = 0; mi < 4; ++mi) {
        #pragma unroll
        for (int ni = 0; ni < 4; ++ni) {
            #pragma unroll
            for (int r = 0; r < 4; ++r) {
                int m = mt * 128 + wr * 64 + mi * 16 + kg * 4 + r;   // fused row b*512+c
                int j = jt * 128 + wc * 64 + ni * 16 + lr;
                out[(size_t)m * 1024 + j] = acc[mi][ni][r] + wb[ni];
            }
        }
    }
}

extern "C" void kernel_launch(void* const* d_in, const int* in_sizes, int n_in,
                              void* d_out, int out_size, void* d_ws, size_t ws_size,
                              hipStream_t stream) {
    const float* X      = (const float*)d_in[0];
    const float* Wq_w   = (const float*)d_in[1];
    const float* Wq_b   = (const float*)d_in[2];
    const float* Wk_w   = (const float*)d_in[3];
    const float* Wk_b   = (const float*)d_in[4];
    const float* Wkey   = (const float*)d_in[5];
    const float* u      = (const float*)d_in[6];
    // d_in[7] = R : analytically reconstructed, never read
    const float* center = (const float*)d_in[8];
    const float* alpha  = (const float*)d_in[9];
    const float* W_w    = (const float*)d_in[10];
    const float* W_b    = (const float*)d_in[11];
    float* out = (float*)d_out;

    // Workspace layout (12 MB, no aliasing; proven ws_size >= 12.25 MB):
    //   0..1 MB   : XtP (bf16 packed fragments)
    //   1..1.5 MB : Q
    //   1.5..2 MB : K
    //   2..4 MB   : Wbf
    //   4..12 MB  : IV
    char* ws = (char*)d_ws;
    unsigned short* XtP  = (unsigned short*)ws;                      // 1 MB
    float*          Qbuf = (float*)(ws + (1024u << 10));             // 512 KB
    float*          Kbuf = (float*)(ws + (1536u << 10));             // 512 KB
    unsigned short* Wbf  = (unsigned short*)(ws + (2048u << 10));    // 2 MB
    unsigned short* IV   = (unsigned short*)(ws + (4096u << 10));    // 8 MB

    prep_fused<<<2176, 256, 0, stream>>>(X, Wq_w, Wq_b, Wk_w, Wk_b, W_w, Qbuf, Kbuf, XtP, Wbf);
    attn_mfma<<<dim3(32, 8, 8), 256, 0, stream>>>(XtP, Qbuf, Kbuf, u, Wkey, center, alpha, IV);
    gemm_out<<<dim3(8, 32), 256, 0, stream>>>(IV, Wbf, W_b, out);
}

// Round 7
// 144.599 us; speedup vs baseline: 3.2536x; 1.0493x over previous
//
#include <hip/hip_runtime.h>
#include <hip/hip_bf16.h>

#define BS   8
#define TT   1024
#define DIN  64
#define NH   8
#define DOUT 1024

typedef __attribute__((ext_vector_type(8))) short bf16x8;
typedef __attribute__((ext_vector_type(8))) unsigned short u16x8;
typedef __attribute__((ext_vector_type(4))) float f32x4;

typedef __attribute__((address_space(3))) unsigned int lds_u32;
typedef const __attribute__((address_space(1))) unsigned int glb_u32;

__device__ __forceinline__ unsigned short f2bf(float f) {
    unsigned int u = __float_as_uint(f);
    u += 0x7fff + ((u >> 16) & 1);          // RNE
    return (unsigned short)(u >> 16);
}

// ---------------- Kernel A: fused prep ----------------
// blocks 0..1023   : qk projection (8 rows each)
// blocks 1024..1151: X -> XtP packed-fragment bf16 transpose
// blocks 1152..2175: W_w -> bf16
__global__ __launch_bounds__(256) void prep_fused(const float* __restrict__ X,
                                                  const float* __restrict__ Wq_w,
                                                  const float* __restrict__ Wq_b,
                                                  const float* __restrict__ Wk_w,
                                                  const float* __restrict__ Wk_b,
                                                  const float* __restrict__ W_w,
                                                  float* __restrict__ Q,
                                                  float* __restrict__ K,
                                                  unsigned short* __restrict__ XtP,
                                                  unsigned short* __restrict__ Wbf) {
    __shared__ float Ws[32][65];
    __shared__ float bsm[32];
    __shared__ float Xs[8][64];
    __shared__ unsigned short S[64][68];

    const int bid = blockIdx.x, tid = threadIdx.x;

    if (bid < 1024) {
        // ---- qk projection ----
        for (int i = tid; i < 2048; i += 256) {
            int r = i >> 6, d = i & 63;
            Ws[r][d] = (r < 16) ? Wq_w[r * 64 + d] : Wk_w[(r - 16) * 64 + d];
        }
        if (tid < 32) bsm[tid] = (tid < 16) ? Wq_b[tid] : Wk_b[tid - 16];
        int row0 = bid * 8;
        for (int i = tid; i < 512; i += 256) {
            int r = i >> 6, d = i & 63;
            Xs[r][d] = X[(size_t)(row0 + r) * 64 + d];
        }
        __syncthreads();
        int r = tid >> 5;
        int j = tid & 31;
        float s = bsm[j];
        #pragma unroll
        for (int d = 0; d < 64; ++d) s = fmaf(Xs[r][d], Ws[j][d], s);
        int row = row0 + r;
        if (j < 16) {
            Q[(size_t)row * 16 + j] = s;
        } else {
            int h = (j - 16) >> 1, d2 = (j - 16) & 1;
            int b = row >> 10, l = row & 1023;
            K[(((size_t)(b * 8 + h)) * 1024 + l) * 2 + d2] = s;
        }
    } else if (bid < 1152) {
        // ---- XtP pack: chunk ((bb*32+lblk)*4+mi)*64+lane holds
        //      X[bb][lblk*32 + (lane>>4)*8 + j][mi*16 + (lane&15)], j=0..7
        int idx = bid - 1024;            // 0..127
        int bb = idx >> 4, lc = idx & 15;
        int l0 = lc * 64;
        int r = tid >> 4;                // 0..15
        int q4 = (tid & 15) * 4;
        #pragma unroll
        for (int p = 0; p < 4; ++p) {
            int row = p * 16 + r;
            float4 v = *(const float4*)(X + ((size_t)(bb * 1024 + l0 + row)) * 64 + q4);
            S[row][q4 + 0] = f2bf(v.x);
            S[row][q4 + 1] = f2bf(v.y);
            S[row][q4 + 2] = f2bf(v.z);
            S[row][q4 + 3] = f2bf(v.w);
        }
        __syncthreads();
        #pragma unroll
        for (int it = 0; it < 2; ++it) {
            int chunk = it * 256 + tid;
            int lane = chunk & 63, mi = (chunk >> 6) & 3, lbr = chunk >> 8;
            int g = lane >> 4, tr = lane & 15;
            int d = mi * 16 + tr;
            int ls = lbr * 32 + g * 8;
            u16x8 o;
            #pragma unroll
            for (int j = 0; j < 8; ++j) o[j] = S[ls + j][d];
            *(u16x8*)(XtP + (size_t)((((bb * 32 + lc * 2 + lbr) * 4 + mi) * 64 + lane)) * 8) = o;
        }
    } else {
        // ---- W_w -> bf16 ----
        int i = (bid - 1152) * 256 + tid;
        float4 v = ((const float4*)W_w)[i];
        ushort4 o;
        o.x = f2bf(v.x); o.y = f2bf(v.y); o.z = f2bf(v.z); o.w = f2bf(v.w);
        ((ushort4*)Wbf)[i] = o;
    }
}

// ---------------- Kernel B: scores + analytic-max softmax + MFMA PV ----------------
// grid (16 t-blocks, 8 h, 8 b), block 512 = 8 waves = 4 t-subtiles x 2 l-halves.
// X fragments staged once per block in LDS (double-buffered global_load_lds);
// each (tsub,lhalf) wave: 16 t rows x 512 l. Partials combined via LDS
// (valid: the softmax max-bound is analytic, identical for both l-halves).
__global__ __launch_bounds__(512, 8) void attn_mfma(const unsigned short* __restrict__ XtP,
                                                    const float* __restrict__ Q,
                                                    const float* __restrict__ K,
                                                    const float* __restrict__ u,
                                                    const float* __restrict__ Wkey,
                                                    const float* __restrict__ center,
                                                    const float* __restrict__ alpha,
                                                    unsigned short* __restrict__ IV) {
    const int h  = blockIdx.y;
    const int bb = blockIdx.z;
    const int tid = threadIdx.x;
    const int w = tid >> 6, lane = tid & 63;
    const int g = lane >> 4, tr = lane & 15;
    const int tsub = w & 3, lhalf = w >> 2;
    const int t = blockIdx.x * 64 + tsub * 16 + tr;

    __shared__ float SH[4352];             // Ks[2048]; after loop reused as C[4][64][17]
    __shared__ unsigned short Xs[2][4096]; // 2 x 8KB X-fragment buffers
    __shared__ float red[8][4];

    // staging source: thread tid covers chunk (tid&255) of lblk {it | 16+it}
    const unsigned short* xsrc = XtP + (size_t)bb * 65536
                               + (size_t)((tid >> 8) * 16) * 2048 + (tid & 255) * 8;

    {   // prologue: stage K[l][2] (this b,h) + X buf0 (it=0)
        const float4* Kg = (const float4*)(K + ((size_t)(bb * 8 + h)) * 2048);
        ((float4*)SH)[tid] = Kg[tid];
        __builtin_amdgcn_global_load_lds((glb_u32*)xsrc, (lds_u32*)(&Xs[0][tid * 8]), 16, 0, 0);
    }
    asm volatile("s_waitcnt vmcnt(0)");
    __syncthreads();

    // block-wide K extrema for the analytic max bound
    float mxp, mxn, myp, myn;
    {
        const float2* K2 = (const float2*)SH;
        float2 ka = K2[tid], kb = K2[tid + 512];
        mxp = fmaxf(ka.x, kb.x); mxn = fminf(ka.x, kb.x);
        myp = fmaxf(ka.y, kb.y); myn = fminf(ka.y, kb.y);
        #pragma unroll
        for (int off = 32; off; off >>= 1) {
            mxp = fmaxf(mxp, __shfl_xor(mxp, off)); mxn = fminf(mxn, __shfl_xor(mxn, off));
            myp = fmaxf(myp, __shfl_xor(myp, off)); myn = fminf(myn, __shfl_xor(myn, off));
        }
        if (lane == 0) { red[w][0] = mxp; red[w][1] = mxn; red[w][2] = myp; red[w][3] = myn; }
    }
    __syncthreads();
    mxp = red[0][0]; mxn = red[0][1]; myp = red[0][2]; myn = red[0][3];
    #pragma unroll
    for (int i = 1; i < 8; ++i) {
        mxp = fmaxf(mxp, red[i][0]); mxn = fminf(mxn, red[i][1]);
        myp = fmaxf(myp, red[i][2]); myn = fminf(myn, red[i][3]);
    }

    const float L2E = 1.4426950408889634f;
    float2 q  = ((const float2*)Q)[(size_t)(bb * 1024 + t) * 8 + h];
    float2 uu = ((const float2*)u)[t];
    const float al = alpha[0];
    const float a0 = (q.x + uu.x) * L2E;
    const float a1 = (q.y + uu.y) * L2E;
    const float p0 = q.x - al;
    const float p1 = q.y + 2.0f * al * center[h];
    const float c0 = (p0 * Wkey[0] + p1 * Wkey[2]) * L2E;
    const float c1 = (p0 * Wkey[1] + p1 * Wkey[3]) * L2E;
    const float tf = (float)t;

    // analytic upper bound on max score
    const float qb = fmaxf(a0 * mxp, a0 * mxn) + fmaxf(a1 * myp, a1 * myn);
    const float dlo = -tf, dhi = 1023.0f - tf;
    float qm = fmaxf(fmaf(fmaf(c0, dlo, c1), dlo, 0.0f),
                     fmaf(fmaf(c0, dhi, c1), dhi, 0.0f));
    if (c0 < 0.0f) {
        float dstar = -c1 / (2.0f * c0);
        if (dstar > dlo && dstar < dhi) qm = -c1 * c1 / (4.0f * c0);
    }
    const float negm = -(qm + qb);

    f32x4 acc[4];
    #pragma unroll
    for (int mi = 0; mi < 4; ++mi) acc[mi] = (f32x4){0.f, 0.f, 0.f, 0.f};
    float sum = 0.f;

    int cur = 0;
    for (int it = 0; it < 16; ++it) {
        // stage next X chunk (both l-halves) into the other buffer
        const int itn = (it + 1) & 15;
        __builtin_amdgcn_global_load_lds((glb_u32*)(xsrc + itn * 2048),
                                         (lds_u32*)(&Xs[cur ^ 1][tid * 8]), 16, 0, 0);

        const int lb = lhalf * 512 + it * 32 + g * 8;
        const float4* kp = (const float4*)SH + (lb >> 1);   // {x0,y0,x1,y1}
        const float dlb = (float)lb - tf;
        union { bf16x8 v; unsigned int wd[4]; } pb;
        #pragma unroll
        for (int jj = 0; jj < 4; ++jj) {
            float4 kv = kp[jj];
            float dl0 = dlb + (float)(2 * jj);
            float dl1 = dl0 + 1.0f;
            float e0 = exp2f(fmaf(fmaf(c0, dl0, c1), dl0, fmaf(a0, kv.x, fmaf(a1, kv.y, negm))));
            float e1 = exp2f(fmaf(fmaf(c0, dl1, c1), dl1, fmaf(a0, kv.z, fmaf(a1, kv.w, negm))));
            sum += e0 + e1;
            asm("v_cvt_pk_bf16_f32 %0, %1, %2" : "=v"(pb.wd[jj]) : "v"(e0), "v"(e1));
        }
        const bf16x8* xv = (const bf16x8*)(&Xs[cur][0]);
        #pragma unroll
        for (int mi = 0; mi < 4; ++mi)
            acc[mi] = __builtin_amdgcn_mfma_f32_16x16x32_bf16(
                xv[lhalf * 256 + mi * 64 + lane], pb.v, acc[mi], 0, 0, 0);

        asm volatile("s_waitcnt vmcnt(0)");
        __syncthreads();
        cur ^= 1;
    }

    sum += __shfl_xor(sum, 16);
    sum += __shfl_xor(sum, 32);

    __syncthreads();                     // done with SH-as-Ks and Xs
    if (lhalf == 1) {
        float* cp = SH + (tsub * 64 + lane) * 17;
        #pragma unroll
        for (int mi = 0; mi < 4; ++mi)
            #pragma unroll
            for (int r = 0; r < 4; ++r) cp[mi * 4 + r] = acc[mi][r];
        cp[16] = sum;
    }
    __syncthreads();
    if (lhalf == 0) {
        const float* cp = SH + (tsub * 64 + lane) * 17;
        #pragma unroll
        for (int mi = 0; mi < 4; ++mi)
            #pragma unroll
            for (int r = 0; r < 4; ++r) acc[mi][r] += cp[mi * 4 + r];
        sum += cp[16];
        const float rinv = 1.0f / sum;
        #pragma unroll
        for (int mi = 0; mi < 4; ++mi) {
            #pragma unroll
            for (int r = 0; r < 4; ++r) {
                int d = mi * 16 + g * 4 + r;
                IV[((size_t)(bb * 512 + h * 64 + d)) * 1024 + t] = f2bf(acc[mi][r] * rinv);
            }
        }
    }
}

// ---------------- Kernel C: out = IV @ W_w^T + W_b ----------------
// Fused M=4096. 128x128 tile, BK=32, double-buffered global_load_lds with XOR
// slot swizzle. grid (8 jt, 32 mt), block 512 = 8 waves (2x4), wave tile 64x32.
__global__ __launch_bounds__(512) void gemm_out(const unsigned short* __restrict__ IV,
                                                const unsigned short* __restrict__ Wbf,
                                                const float* __restrict__ W_b,
                                                float* __restrict__ out) {
    const int jt = blockIdx.x;      // 0..7
    const int mt = blockIdx.y;      // 0..31
    const int tid = threadIdx.x;
    const int w = tid >> 6, lane = tid & 63;
    const int lr = lane & 15, kg = lane >> 4;
    const int wr = w >> 2, wc = w & 3;

    __shared__ unsigned short As[2][4096];   // 8KB per buffer
    __shared__ unsigned short Bs[2][4096];

    // staging: thread tid covers chunk (row=tid>>2, phys slot=tid&3)
    const int r0 = tid >> 2, s0 = tid & 3;
    const int kgA = s0 ^ ((r0 >> 1) & 3);
    const unsigned short* Ag = IV  + (size_t)(mt * 128 + r0) * 1024 + kgA * 8;
    const unsigned short* Bg = Wbf + (size_t)(jt * 128 + r0) * 1024 + kgA * 8;

#define STAGE(bufi, kk) do {                                                                          \
    __builtin_amdgcn_global_load_lds((glb_u32*)(Ag + (kk)), (lds_u32*)(&As[bufi][tid * 8]), 16, 0, 0); \
    __builtin_amdgcn_global_load_lds((glb_u32*)(Bg + (kk)), (lds_u32*)(&Bs[bufi][tid * 8]), 16, 0, 0); \
} while (0)

    f32x4 acc[4][2];
    #pragma unroll
    for (int mi = 0; mi < 4; ++mi)
        #pragma unroll
        for (int ni = 0; ni < 2; ++ni)
            acc[mi][ni] = (f32x4){0.f, 0.f, 0.f, 0.f};

    STAGE(0, 0);
    asm volatile("s_waitcnt vmcnt(0)");
    __syncthreads();

    const int slot = kg ^ ((lr >> 1) & 3);        // same involution as the write side
    int cur = 0;
    for (int kt = 0; kt < 32; ++kt) {
        if (kt < 31) STAGE(cur ^ 1, (kt + 1) * 32);
        bf16x8 af[4], bfr[2];
        #pragma unroll
        for (int mi = 0; mi < 4; ++mi) {
            int row = wr * 64 + mi * 16 + lr;
            af[mi] = *(const bf16x8*)(&As[cur][row * 32 + slot * 8]);
        }
        #pragma unroll
        for (int ni = 0; ni < 2; ++ni) {
            int row = wc * 32 + ni * 16 + lr;
            bfr[ni] = *(const bf16x8*)(&Bs[cur][row * 32 + slot * 8]);
        }
        #pragma unroll
        for (int mi = 0; mi < 4; ++mi)
            #pragma unroll
            for (int ni = 0; ni < 2; ++ni)
                acc[mi][ni] = __builtin_amdgcn_mfma_f32_16x16x32_bf16(
                    af[mi], bfr[ni], acc[mi][ni], 0, 0, 0);
        asm volatile("s_waitcnt vmcnt(0)");
        __syncthreads();
        cur ^= 1;
    }
#undef STAGE

    float wb[2];
    #pragma unroll
    for (int ni = 0; ni < 2; ++ni) wb[ni] = W_b[jt * 128 + wc * 32 + ni * 16 + lr];

    #pragma unroll
    for (int mi = 0; mi < 4; ++mi) {
        #pragma unroll
        for (int ni = 0; ni < 2; ++ni) {
            #pragma unroll
            for (int r = 0; r < 4; ++r) {
                int m = mt * 128 + wr * 64 + mi * 16 + kg * 4 + r;   // fused row b*512+c
                int j = jt * 128 + wc * 32 + ni * 16 + lr;
                out[(size_t)m * 1024 + j] = acc[mi][ni][r] + wb[ni];
            }
        }
    }
}

extern "C" void kernel_launch(void* const* d_in, const int* in_sizes, int n_in,
                              void* d_out, int out_size, void* d_ws, size_t ws_size,
                              hipStream_t stream) {
    const float* X      = (const float*)d_in[0];
    const float* Wq_w   = (const float*)d_in[1];
    const float* Wq_b   = (const float*)d_in[2];
    const float* Wk_w   = (const float*)d_in[3];
    const float* Wk_b   = (const float*)d_in[4];
    const float* Wkey   = (const float*)d_in[5];
    const float* u      = (const float*)d_in[6];
    // d_in[7] = R : analytically reconstructed, never read
    const float* center = (const float*)d_in[8];
    const float* alpha  = (const float*)d_in[9];
    const float* W_w    = (const float*)d_in[10];
    const float* W_b    = (const float*)d_in[11];
    float* out = (float*)d_out;

    // Workspace layout (12 MB, no aliasing; proven ws_size >= 12.25 MB):
    //   0..1 MB   : XtP (bf16 packed fragments)
    //   1..1.5 MB : Q
    //   1.5..2 MB : K
    //   2..4 MB   : Wbf
    //   4..12 MB  : IV
    char* ws = (char*)d_ws;
    unsigned short* XtP  = (unsigned short*)ws;                      // 1 MB
    float*          Qbuf = (float*)(ws + (1024u << 10));             // 512 KB
    float*          Kbuf = (float*)(ws + (1536u << 10));             // 512 KB
    unsigned short* Wbf  = (unsigned short*)(ws + (2048u << 10));    // 2 MB
    unsigned short* IV   = (unsigned short*)(ws + (4096u << 10));    // 8 MB

    prep_fused<<<2176, 256, 0, stream>>>(X, Wq_w, Wq_b, Wk_w, Wk_b, W_w, Qbuf, Kbuf, XtP, Wbf);
    attn_mfma<<<dim3(16, 8, 8), 512, 0, stream>>>(XtP, Qbuf, Kbuf, u, Wkey, center, alpha, IV);
    gemm_out<<<dim3(8, 32), 512, 0, stream>>>(IV, Wbf, W_b, out);
}

// Round 8
// 141.313 us; speedup vs baseline: 3.3293x; 1.0233x over previous
//
#include <hip/hip_runtime.h>
#include <hip/hip_bf16.h>

#define BS   8
#define TT   1024
#define DIN  64
#define NH   8
#define DOUT 1024

typedef __attribute__((ext_vector_type(8))) short bf16x8;
typedef __attribute__((ext_vector_type(8))) unsigned short u16x8;
typedef __attribute__((ext_vector_type(4))) float f32x4;

typedef __attribute__((address_space(3))) unsigned int lds_u32;
typedef const __attribute__((address_space(1))) unsigned int glb_u32;

__device__ __forceinline__ unsigned short f2bf(float f) {
    unsigned int u = __float_as_uint(f);
    u += 0x7fff + ((u >> 16) & 1);          // RNE
    return (unsigned short)(u >> 16);
}

// ---------------- Kernel A: fused prep ----------------
// blocks 0..1023   : qk projection (8 rows each)
// blocks 1024..1151: X -> XtP packed-fragment bf16 transpose
// blocks 1152..2175: W_w -> bf16
__global__ __launch_bounds__(256) void prep_fused(const float* __restrict__ X,
                                                  const float* __restrict__ Wq_w,
                                                  const float* __restrict__ Wq_b,
                                                  const float* __restrict__ Wk_w,
                                                  const float* __restrict__ Wk_b,
                                                  const float* __restrict__ W_w,
                                                  float* __restrict__ Q,
                                                  float* __restrict__ K,
                                                  unsigned short* __restrict__ XtP,
                                                  unsigned short* __restrict__ Wbf) {
    __shared__ float Ws[32][65];
    __shared__ float bsm[32];
    __shared__ float Xs[8][64];
    __shared__ unsigned short S[64][68];

    const int bid = blockIdx.x, tid = threadIdx.x;

    if (bid < 1024) {
        // ---- qk projection ----
        for (int i = tid; i < 2048; i += 256) {
            int r = i >> 6, d = i & 63;
            Ws[r][d] = (r < 16) ? Wq_w[r * 64 + d] : Wk_w[(r - 16) * 64 + d];
        }
        if (tid < 32) bsm[tid] = (tid < 16) ? Wq_b[tid] : Wk_b[tid - 16];
        int row0 = bid * 8;
        for (int i = tid; i < 512; i += 256) {
            int r = i >> 6, d = i & 63;
            Xs[r][d] = X[(size_t)(row0 + r) * 64 + d];
        }
        __syncthreads();
        int r = tid >> 5;
        int j = tid & 31;
        float s = bsm[j];
        #pragma unroll
        for (int d = 0; d < 64; ++d) s = fmaf(Xs[r][d], Ws[j][d], s);
        int row = row0 + r;
        if (j < 16) {
            Q[(size_t)row * 16 + j] = s;
        } else {
            int h = (j - 16) >> 1, d2 = (j - 16) & 1;
            int b = row >> 10, l = row & 1023;
            K[(((size_t)(b * 8 + h)) * 1024 + l) * 2 + d2] = s;
        }
    } else if (bid < 1152) {
        // ---- XtP pack: chunk ((bb*32+lblk)*4+mi)*64+lane holds
        //      X[bb][lblk*32 + (lane>>4)*8 + j][mi*16 + (lane&15)], j=0..7
        int idx = bid - 1024;            // 0..127
        int bb = idx >> 4, lc = idx & 15;
        int l0 = lc * 64;
        int r = tid >> 4;                // 0..15
        int q4 = (tid & 15) * 4;
        #pragma unroll
        for (int p = 0; p < 4; ++p) {
            int row = p * 16 + r;
            float4 v = *(const float4*)(X + ((size_t)(bb * 1024 + l0 + row)) * 64 + q4);
            S[row][q4 + 0] = f2bf(v.x);
            S[row][q4 + 1] = f2bf(v.y);
            S[row][q4 + 2] = f2bf(v.z);
            S[row][q4 + 3] = f2bf(v.w);
        }
        __syncthreads();
        #pragma unroll
        for (int it = 0; it < 2; ++it) {
            int chunk = it * 256 + tid;
            int lane = chunk & 63, mi = (chunk >> 6) & 3, lbr = chunk >> 8;
            int g = lane >> 4, tr = lane & 15;
            int d = mi * 16 + tr;
            int ls = lbr * 32 + g * 8;
            u16x8 o;
            #pragma unroll
            for (int j = 0; j < 8; ++j) o[j] = S[ls + j][d];
            *(u16x8*)(XtP + (size_t)((((bb * 32 + lc * 2 + lbr) * 4 + mi) * 64 + lane)) * 8) = o;
        }
    } else {
        // ---- W_w -> bf16 ----
        int i = (bid - 1152) * 256 + tid;
        float4 v = ((const float4*)W_w)[i];
        ushort4 o;
        o.x = f2bf(v.x); o.y = f2bf(v.y); o.z = f2bf(v.z); o.w = f2bf(v.w);
        ((ushort4*)Wbf)[i] = o;
    }
}

// ---------------- Kernel B: scores + analytic-max softmax + MFMA PV ----------------
// grid (16 t-blocks, 8 h, 8 b), block 512 = 8 waves = 4 t-subtiles x 2 l-halves.
// X fragments staged once per block in LDS (double-buffered global_load_lds);
// each (tsub,lhalf) wave: 16 t rows x 512 l. Partials combined via LDS
// (valid: the softmax max-bound is analytic, identical for both l-halves).
__global__ __launch_bounds__(512, 8) void attn_mfma(const unsigned short* __restrict__ XtP,
                                                    const float* __restrict__ Q,
                                                    const float* __restrict__ K,
                                                    const float* __restrict__ u,
                                                    const float* __restrict__ Wkey,
                                                    const float* __restrict__ center,
                                                    const float* __restrict__ alpha,
                                                    unsigned short* __restrict__ IV) {
    const int h  = blockIdx.y;
    const int bb = blockIdx.z;
    const int tid = threadIdx.x;
    const int w = tid >> 6, lane = tid & 63;
    const int g = lane >> 4, tr = lane & 15;
    const int tsub = w & 3, lhalf = w >> 2;
    const int t = blockIdx.x * 64 + tsub * 16 + tr;

    __shared__ float SH[4352];             // Ks[2048]; after loop reused as C[4][64][17]
    __shared__ unsigned short Xs[2][4096]; // 2 x 8KB X-fragment buffers
    __shared__ float red[8][4];

    // staging source: thread tid covers chunk (tid&255) of lblk {it | 16+it}
    const unsigned short* xsrc = XtP + (size_t)bb * 65536
                               + (size_t)((tid >> 8) * 16) * 2048 + (tid & 255) * 8;

    {   // prologue: stage K[l][2] (this b,h) + X buf0 (it=0)
        const float4* Kg = (const float4*)(K + ((size_t)(bb * 8 + h)) * 2048);
        ((float4*)SH)[tid] = Kg[tid];
        __builtin_amdgcn_global_load_lds((glb_u32*)xsrc, (lds_u32*)(&Xs[0][tid * 8]), 16, 0, 0);
    }
    asm volatile("s_waitcnt vmcnt(0)");
    __syncthreads();

    // block-wide K extrema for the analytic max bound
    float mxp, mxn, myp, myn;
    {
        const float2* K2 = (const float2*)SH;
        float2 ka = K2[tid], kb = K2[tid + 512];
        mxp = fmaxf(ka.x, kb.x); mxn = fminf(ka.x, kb.x);
        myp = fmaxf(ka.y, kb.y); myn = fminf(ka.y, kb.y);
        #pragma unroll
        for (int off = 32; off; off >>= 1) {
            mxp = fmaxf(mxp, __shfl_xor(mxp, off)); mxn = fminf(mxn, __shfl_xor(mxn, off));
            myp = fmaxf(myp, __shfl_xor(myp, off)); myn = fminf(myn, __shfl_xor(myn, off));
        }
        if (lane == 0) { red[w][0] = mxp; red[w][1] = mxn; red[w][2] = myp; red[w][3] = myn; }
    }
    __syncthreads();
    mxp = red[0][0]; mxn = red[0][1]; myp = red[0][2]; myn = red[0][3];
    #pragma unroll
    for (int i = 1; i < 8; ++i) {
        mxp = fmaxf(mxp, red[i][0]); mxn = fminf(mxn, red[i][1]);
        myp = fmaxf(myp, red[i][2]); myn = fminf(myn, red[i][3]);
    }

    const float L2E = 1.4426950408889634f;
    float2 q  = ((const float2*)Q)[(size_t)(bb * 1024 + t) * 8 + h];
    float2 uu = ((const float2*)u)[t];
    const float al = alpha[0];
    const float a0 = (q.x + uu.x) * L2E;
    const float a1 = (q.y + uu.y) * L2E;
    const float p0 = q.x - al;
    const float p1 = q.y + 2.0f * al * center[h];
    const float c0 = (p0 * Wkey[0] + p1 * Wkey[2]) * L2E;
    const float c1 = (p0 * Wkey[1] + p1 * Wkey[3]) * L2E;
    const float tf = (float)t;

    // analytic upper bound on max score
    const float qb = fmaxf(a0 * mxp, a0 * mxn) + fmaxf(a1 * myp, a1 * myn);
    const float dlo = -tf, dhi = 1023.0f - tf;
    float qm = fmaxf(fmaf(fmaf(c0, dlo, c1), dlo, 0.0f),
                     fmaf(fmaf(c0, dhi, c1), dhi, 0.0f));
    if (c0 < 0.0f) {
        float dstar = -c1 / (2.0f * c0);
        if (dstar > dlo && dstar < dhi) qm = -c1 * c1 / (4.0f * c0);
    }
    const float negm = -(qm + qb);

    f32x4 acc[4];
    #pragma unroll
    for (int mi = 0; mi < 4; ++mi) acc[mi] = (f32x4){0.f, 0.f, 0.f, 0.f};
    float sum = 0.f;

    int cur = 0;
    for (int it = 0; it < 16; ++it) {
        // stage next X chunk (both l-halves) into the other buffer
        const int itn = (it + 1) & 15;
        __builtin_amdgcn_global_load_lds((glb_u32*)(xsrc + itn * 2048),
                                         (lds_u32*)(&Xs[cur ^ 1][tid * 8]), 16, 0, 0);

        const int lb = lhalf * 512 + it * 32 + g * 8;
        const float4* kp = (const float4*)SH + (lb >> 1);   // {x0,y0,x1,y1}
        const float dlb = (float)lb - tf;
        union { bf16x8 v; unsigned int wd[4]; } pb;
        #pragma unroll
        for (int jj = 0; jj < 4; ++jj) {
            float4 kv = kp[jj];
            float dl0 = dlb + (float)(2 * jj);
            float dl1 = dl0 + 1.0f;
            float e0 = exp2f(fmaf(fmaf(c0, dl0, c1), dl0, fmaf(a0, kv.x, fmaf(a1, kv.y, negm))));
            float e1 = exp2f(fmaf(fmaf(c0, dl1, c1), dl1, fmaf(a0, kv.z, fmaf(a1, kv.w, negm))));
            sum += e0 + e1;
            asm("v_cvt_pk_bf16_f32 %0, %1, %2" : "=v"(pb.wd[jj]) : "v"(e0), "v"(e1));
        }
        const bf16x8* xv = (const bf16x8*)(&Xs[cur][0]);
        #pragma unroll
        for (int mi = 0; mi < 4; ++mi)
            acc[mi] = __builtin_amdgcn_mfma_f32_16x16x32_bf16(
                xv[lhalf * 256 + mi * 64 + lane], pb.v, acc[mi], 0, 0, 0);

        asm volatile("s_waitcnt vmcnt(0)");
        __syncthreads();
        cur ^= 1;
    }

    sum += __shfl_xor(sum, 16);
    sum += __shfl_xor(sum, 32);

    __syncthreads();                     // done with SH-as-Ks and Xs
    if (lhalf == 1) {
        float* cp = SH + (tsub * 64 + lane) * 17;
        #pragma unroll
        for (int mi = 0; mi < 4; ++mi)
            #pragma unroll
            for (int r = 0; r < 4; ++r) cp[mi * 4 + r] = acc[mi][r];
        cp[16] = sum;
    }
    __syncthreads();
    if (lhalf == 0) {
        const float* cp = SH + (tsub * 64 + lane) * 17;
        #pragma unroll
        for (int mi = 0; mi < 4; ++mi)
            #pragma unroll
            for (int r = 0; r < 4; ++r) acc[mi][r] += cp[mi * 4 + r];
        sum += cp[16];
        const float rinv = 1.0f / sum;
        #pragma unroll
        for (int mi = 0; mi < 4; ++mi) {
            #pragma unroll
            for (int r = 0; r < 4; ++r) {
                int d = mi * 16 + g * 4 + r;
                IV[((size_t)(bb * 512 + h * 64 + d)) * 1024 + t] = f2bf(acc[mi][r] * rinv);
            }
        }
    }
}

// ---------------- Kernel C: out = IV @ W_w^T + W_b ----------------
// Fused M=4096, tile 128m x 64n, BK=32, 3-buffer global_load_lds pipeline with
// counted vmcnt (never drains to 0 mid-loop) + one raw s_barrier per K-step.
// XOR slot swizzle identical to the proven round-7 involution.
// grid (16 jt, 32 mt) = 512 blocks (2/CU), block 256 = 4 waves, wave 64x32.
__global__ __launch_bounds__(256) void gemm_out(const unsigned short* __restrict__ IV,
                                                const unsigned short* __restrict__ Wbf,
                                                const float* __restrict__ W_b,
                                                float* __restrict__ out) {
    const int jt = blockIdx.x;      // 0..15 (64 cols each)
    const int mt = blockIdx.y;      // 0..31 (128 rows each)
    const int tid = threadIdx.x;
    const int w = tid >> 6, lane = tid & 63;
    const int lr = lane & 15, kg = lane >> 4;
    const int wr = w >> 1, wc = w & 1;

    __shared__ unsigned short As[3][4096];   // 3 x 8KB
    __shared__ unsigned short Bs[3][2048];   // 3 x 4KB

    // staging: chunk c -> row c>>2, phys slot c&3; kg_written = slot ^ ((row>>1)&3).
    // Rows r and r+64 share ((row>>1)&3), so one kga serves both A sub-loads.
    const int r0 = tid >> 2, s0 = tid & 3;
    const int kga = s0 ^ ((r0 >> 1) & 3);
    const unsigned short* Ag0 = IV  + (size_t)(mt * 128 + r0) * 1024 + kga * 8;
    const unsigned short* Ag1 = Ag0 + (size_t)64 * 1024;
    const unsigned short* Bg  = Wbf + (size_t)(jt * 64 + r0) * 1024 + kga * 8;

#define STAGE(bufi, kk) do {                                                                           \
    __builtin_amdgcn_global_load_lds((glb_u32*)(Ag0 + (kk)), (lds_u32*)(&As[bufi][tid * 8]), 16, 0, 0); \
    __builtin_amdgcn_global_load_lds((glb_u32*)(Ag1 + (kk)), (lds_u32*)(&As[bufi][(tid + 256) * 8]), 16, 0, 0); \
    __builtin_amdgcn_global_load_lds((glb_u32*)(Bg  + (kk)), (lds_u32*)(&Bs[bufi][tid * 8]), 16, 0, 0); \
} while (0)

    f32x4 acc[4][2];
    #pragma unroll
    for (int mi = 0; mi < 4; ++mi)
        #pragma unroll
        for (int ni = 0; ni < 2; ++ni)
            acc[mi][ni] = (f32x4){0.f, 0.f, 0.f, 0.f};

    STAGE(0, 0);
    STAGE(1, 32);

    const int slot = kg ^ ((lr >> 1) & 3);        // read-side involution (matches write)

    #pragma unroll
    for (int kt = 0; kt < 32; ++kt) {
        // Wait own stage-kt loads (3), leave stage-(kt+1)'s 3 in flight.
        if (kt < 31) asm volatile("s_waitcnt vmcnt(3)" ::: "memory");
        else         asm volatile("s_waitcnt vmcnt(0)" ::: "memory");
        __builtin_amdgcn_s_barrier();              // all waves' stage-kt data visible;
        __builtin_amdgcn_sched_barrier(0);         // pin: no ds_read hoisted above barrier
        // Issue stage kt+2 into buf (kt+2)%3 -- last read at iter kt-1, whose
        // ds_reads completed before this barrier (consumed by its MFMAs).
        if (kt < 30) STAGE((kt + 2) % 3, (kt + 2) * 32);

        const int cur = kt % 3;
        bf16x8 af[4], bfr[2];
        #pragma unroll
        for (int mi = 0; mi < 4; ++mi) {
            int row = wr * 64 + mi * 16 + lr;
            af[mi] = *(const bf16x8*)(&As[cur][row * 32 + slot * 8]);
        }
        #pragma unroll
        for (int ni = 0; ni < 2; ++ni) {
            int row = wc * 32 + ni * 16 + lr;
            bfr[ni] = *(const bf16x8*)(&Bs[cur][row * 32 + slot * 8]);
        }
        #pragma unroll
        for (int mi = 0; mi < 4; ++mi)
            #pragma unroll
            for (int ni = 0; ni < 2; ++ni)
                acc[mi][ni] = __builtin_amdgcn_mfma_f32_16x16x32_bf16(
                    af[mi], bfr[ni], acc[mi][ni], 0, 0, 0);
    }
#undef STAGE

    float wb[2];
    #pragma unroll
    for (int ni = 0; ni < 2; ++ni) wb[ni] = W_b[jt * 64 + wc * 32 + ni * 16 + lr];

    #pragma unroll
    for (int mi = 0; mi < 4; ++mi) {
        #pragma unroll
        for (int ni = 0; ni < 2; ++ni) {
            #pragma unroll
            for (int r = 0; r < 4; ++r) {
                int m = mt * 128 + wr * 64 + mi * 16 + kg * 4 + r;   // fused row b*512+c
                int j = jt * 64 + wc * 32 + ni * 16 + lr;
                out[(size_t)m * 1024 + j] = acc[mi][ni][r] + wb[ni];
            }
        }
    }
}

extern "C" void kernel_launch(void* const* d_in, const int* in_sizes, int n_in,
                              void* d_out, int out_size, void* d_ws, size_t ws_size,
                              hipStream_t stream) {
    const float* X      = (const float*)d_in[0];
    const float* Wq_w   = (const float*)d_in[1];
    const float* Wq_b   = (const float*)d_in[2];
    const float* Wk_w   = (const float*)d_in[3];
    const float* Wk_b   = (const float*)d_in[4];
    const float* Wkey   = (const float*)d_in[5];
    const float* u      = (const float*)d_in[6];
    // d_in[7] = R : analytically reconstructed, never read
    const float* center = (const float*)d_in[8];
    const float* alpha  = (const float*)d_in[9];
    const float* W_w    = (const float*)d_in[10];
    const float* W_b    = (const float*)d_in[11];
    float* out = (float*)d_out;

    // Workspace layout (12 MB, no aliasing; proven ws_size >= 12.25 MB):
    //   0..1 MB   : XtP (bf16 packed fragments)
    //   1..1.5 MB : Q
    //   1.5..2 MB : K
    //   2..4 MB   : Wbf
    //   4..12 MB  : IV
    char* ws = (char*)d_ws;
    unsigned short* XtP  = (unsigned short*)ws;                      // 1 MB
    float*          Qbuf = (float*)(ws + (1024u << 10));             // 512 KB
    float*          Kbuf = (float*)(ws + (1536u << 10));             // 512 KB
    unsigned short* Wbf  = (unsigned short*)(ws + (2048u << 10));    // 2 MB
    unsigned short* IV   = (unsigned short*)(ws + (4096u << 10));    // 8 MB

    prep_fused<<<2176, 256, 0, stream>>>(X, Wq_w, Wq_b, Wk_w, Wk_b, W_w, Qbuf, Kbuf, XtP, Wbf);
    attn_mfma<<<dim3(16, 8, 8), 512, 0, stream>>>(XtP, Qbuf, Kbuf, u, Wkey, center, alpha, IV);
    gemm_out<<<dim3(16, 32), 256, 0, stream>>>(IV, Wbf, W_b, out);
}

// Round 9
// 140.037 us; speedup vs baseline: 3.3596x; 1.0091x over previous
//
#include <hip/hip_runtime.h>
#include <hip/hip_bf16.h>

#define BS   8
#define TT   1024
#define DIN  64
#define NH   8
#define DOUT 1024

typedef __attribute__((ext_vector_type(8))) short bf16x8;
typedef __attribute__((ext_vector_type(8))) unsigned short u16x8;
typedef __attribute__((ext_vector_type(4))) float f32x4;

typedef __attribute__((address_space(3))) unsigned int lds_u32;
typedef const __attribute__((address_space(1))) unsigned int glb_u32;

__device__ __forceinline__ unsigned short f2bf(float f) {
    unsigned int u = __float_as_uint(f);
    u += 0x7fff + ((u >> 16) & 1);          // RNE
    return (unsigned short)(u >> 16);
}

// ---------------- Kernel A: fused prep ----------------
// blocks 0..1023   : qk projection (8 rows each)
// blocks 1024..1151: X -> XtP packed-fragment bf16 transpose
// blocks 1152..2175: W_w -> bf16
__global__ __launch_bounds__(256) void prep_fused(const float* __restrict__ X,
                                                  const float* __restrict__ Wq_w,
                                                  const float* __restrict__ Wq_b,
                                                  const float* __restrict__ Wk_w,
                                                  const float* __restrict__ Wk_b,
                                                  const float* __restrict__ W_w,
                                                  float* __restrict__ Q,
                                                  float* __restrict__ K,
                                                  unsigned short* __restrict__ XtP,
                                                  unsigned short* __restrict__ Wbf) {
    __shared__ float Ws[32][65];
    __shared__ float bsm[32];
    __shared__ float Xs[8][64];
    __shared__ unsigned short S[64][68];

    const int bid = blockIdx.x, tid = threadIdx.x;

    if (bid < 1024) {
        // ---- qk projection ----
        for (int i = tid; i < 2048; i += 256) {
            int r = i >> 6, d = i & 63;
            Ws[r][d] = (r < 16) ? Wq_w[r * 64 + d] : Wk_w[(r - 16) * 64 + d];
        }
        if (tid < 32) bsm[tid] = (tid < 16) ? Wq_b[tid] : Wk_b[tid - 16];
        int row0 = bid * 8;
        for (int i = tid; i < 512; i += 256) {
            int r = i >> 6, d = i & 63;
            Xs[r][d] = X[(size_t)(row0 + r) * 64 + d];
        }
        __syncthreads();
        int r = tid >> 5;
        int j = tid & 31;
        float s = bsm[j];
        #pragma unroll
        for (int d = 0; d < 64; ++d) s = fmaf(Xs[r][d], Ws[j][d], s);
        int row = row0 + r;
        if (j < 16) {
            Q[(size_t)row * 16 + j] = s;
        } else {
            int h = (j - 16) >> 1, d2 = (j - 16) & 1;
            int b = row >> 10, l = row & 1023;
            K[(((size_t)(b * 8 + h)) * 1024 + l) * 2 + d2] = s;
        }
    } else if (bid < 1152) {
        // ---- XtP pack: chunk ((bb*32+lblk)*4+mi)*64+lane holds
        //      X[bb][lblk*32 + (lane>>4)*8 + j][mi*16 + (lane&15)], j=0..7
        int idx = bid - 1024;            // 0..127
        int bb = idx >> 4, lc = idx & 15;
        int l0 = lc * 64;
        int r = tid >> 4;                // 0..15
        int q4 = (tid & 15) * 4;
        #pragma unroll
        for (int p = 0; p < 4; ++p) {
            int row = p * 16 + r;
            float4 v = *(const float4*)(X + ((size_t)(bb * 1024 + l0 + row)) * 64 + q4);
            S[row][q4 + 0] = f2bf(v.x);
            S[row][q4 + 1] = f2bf(v.y);
            S[row][q4 + 2] = f2bf(v.z);
            S[row][q4 + 3] = f2bf(v.w);
        }
        __syncthreads();
        #pragma unroll
        for (int it = 0; it < 2; ++it) {
            int chunk = it * 256 + tid;
            int lane = chunk & 63, mi = (chunk >> 6) & 3, lbr = chunk >> 8;
            int g = lane >> 4, tr = lane & 15;
            int d = mi * 16 + tr;
            int ls = lbr * 32 + g * 8;
            u16x8 o;
            #pragma unroll
            for (int j = 0; j < 8; ++j) o[j] = S[ls + j][d];
            *(u16x8*)(XtP + (size_t)((((bb * 32 + lc * 2 + lbr) * 4 + mi) * 64 + lane)) * 8) = o;
        }
    } else {
        // ---- W_w -> bf16 ----
        int i = (bid - 1152) * 256 + tid;
        float4 v = ((const float4*)W_w)[i];
        ushort4 o;
        o.x = f2bf(v.x); o.y = f2bf(v.y); o.z = f2bf(v.z); o.w = f2bf(v.w);
        ((ushort4*)Wbf)[i] = o;
    }
}

// ---------------- Kernel B: scores + analytic-max softmax + MFMA PV ----------------
// grid (16 t-blocks, 8 h, 8 b), block 512 = 8 waves = 4 t-subtiles x 2 l-halves.
// X fragments staged once per block in LDS (double-buffered global_load_lds);
// each (tsub,lhalf) wave: 16 t rows x 512 l. Partials combined via LDS
// (valid: the softmax max-bound is analytic, identical for both l-halves).
__global__ __launch_bounds__(512, 8) void attn_mfma(const unsigned short* __restrict__ XtP,
                                                    const float* __restrict__ Q,
                                                    const float* __restrict__ K,
                                                    const float* __restrict__ u,
                                                    const float* __restrict__ Wkey,
                                                    const float* __restrict__ center,
                                                    const float* __restrict__ alpha,
                                                    unsigned short* __restrict__ IV) {
    const int h  = blockIdx.y;
    const int bb = blockIdx.z;
    const int tid = threadIdx.x;
    const int w = tid >> 6, lane = tid & 63;
    const int g = lane >> 4, tr = lane & 15;
    const int tsub = w & 3, lhalf = w >> 2;
    const int t = blockIdx.x * 64 + tsub * 16 + tr;

    __shared__ float SH[4352];             // Ks[2048]; after loop reused as C[4][64][17]
    __shared__ unsigned short Xs[2][4096]; // 2 x 8KB X-fragment buffers
    __shared__ float red[8][4];

    // staging source: thread tid covers chunk (tid&255) of lblk {it | 16+it}
    const unsigned short* xsrc = XtP + (size_t)bb * 65536
                               + (size_t)((tid >> 8) * 16) * 2048 + (tid & 255) * 8;

    {   // prologue: stage K[l][2] (this b,h) + X buf0 (it=0)
        const float4* Kg = (const float4*)(K + ((size_t)(bb * 8 + h)) * 2048);
        ((float4*)SH)[tid] = Kg[tid];
        __builtin_amdgcn_global_load_lds((glb_u32*)xsrc, (lds_u32*)(&Xs[0][tid * 8]), 16, 0, 0);
    }
    asm volatile("s_waitcnt vmcnt(0)");
    __syncthreads();

    // block-wide K extrema for the analytic max bound
    float mxp, mxn, myp, myn;
    {
        const float2* K2 = (const float2*)SH;
        float2 ka = K2[tid], kb = K2[tid + 512];
        mxp = fmaxf(ka.x, kb.x); mxn = fminf(ka.x, kb.x);
        myp = fmaxf(ka.y, kb.y); myn = fminf(ka.y, kb.y);
        #pragma unroll
        for (int off = 32; off; off >>= 1) {
            mxp = fmaxf(mxp, __shfl_xor(mxp, off)); mxn = fminf(mxn, __shfl_xor(mxn, off));
            myp = fmaxf(myp, __shfl_xor(myp, off)); myn = fminf(myn, __shfl_xor(myn, off));
        }
        if (lane == 0) { red[w][0] = mxp; red[w][1] = mxn; red[w][2] = myp; red[w][3] = myn; }
    }
    __syncthreads();
    mxp = red[0][0]; mxn = red[0][1]; myp = red[0][2]; myn = red[0][3];
    #pragma unroll
    for (int i = 1; i < 8; ++i) {
        mxp = fmaxf(mxp, red[i][0]); mxn = fminf(mxn, red[i][1]);
        myp = fmaxf(myp, red[i][2]); myn = fminf(myn, red[i][3]);
    }

    const float L2E = 1.4426950408889634f;
    float2 q  = ((const float2*)Q)[(size_t)(bb * 1024 + t) * 8 + h];
    float2 uu = ((const float2*)u)[t];
    const float al = alpha[0];
    const float a0 = (q.x + uu.x) * L2E;
    const float a1 = (q.y + uu.y) * L2E;
    const float p0 = q.x - al;
    const float p1 = q.y + 2.0f * al * center[h];
    const float c0 = (p0 * Wkey[0] + p1 * Wkey[2]) * L2E;
    const float c1 = (p0 * Wkey[1] + p1 * Wkey[3]) * L2E;
    const float tf = (float)t;

    // analytic upper bound on max score
    const float qb = fmaxf(a0 * mxp, a0 * mxn) + fmaxf(a1 * myp, a1 * myn);
    const float dlo = -tf, dhi = 1023.0f - tf;
    float qm = fmaxf(fmaf(fmaf(c0, dlo, c1), dlo, 0.0f),
                     fmaf(fmaf(c0, dhi, c1), dhi, 0.0f));
    if (c0 < 0.0f) {
        float dstar = -c1 / (2.0f * c0);
        if (dstar > dlo && dstar < dhi) qm = -c1 * c1 / (4.0f * c0);
    }
    const float negm = -(qm + qb);

    f32x4 acc[4];
    #pragma unroll
    for (int mi = 0; mi < 4; ++mi) acc[mi] = (f32x4){0.f, 0.f, 0.f, 0.f};
    float sum = 0.f;

    int cur = 0;
    for (int it = 0; it < 16; ++it) {
        // stage next X chunk (both l-halves) into the other buffer
        const int itn = (it + 1) & 15;
        __builtin_amdgcn_global_load_lds((glb_u32*)(xsrc + itn * 2048),
                                         (lds_u32*)(&Xs[cur ^ 1][tid * 8]), 16, 0, 0);

        const int lb = lhalf * 512 + it * 32 + g * 8;
        const float4* kp = (const float4*)SH + (lb >> 1);   // {x0,y0,x1,y1}
        const float dlb = (float)lb - tf;
        union { bf16x8 v; unsigned int wd[4]; } pb;
        #pragma unroll
        for (int jj = 0; jj < 4; ++jj) {
            float4 kv = kp[jj];
            float dl0 = dlb + (float)(2 * jj);
            float dl1 = dl0 + 1.0f;
            float e0 = exp2f(fmaf(fmaf(c0, dl0, c1), dl0, fmaf(a0, kv.x, fmaf(a1, kv.y, negm))));
            float e1 = exp2f(fmaf(fmaf(c0, dl1, c1), dl1, fmaf(a0, kv.z, fmaf(a1, kv.w, negm))));
            sum += e0 + e1;
            asm("v_cvt_pk_bf16_f32 %0, %1, %2" : "=v"(pb.wd[jj]) : "v"(e0), "v"(e1));
        }
        const bf16x8* xv = (const bf16x8*)(&Xs[cur][0]);
        #pragma unroll
        for (int mi = 0; mi < 4; ++mi)
            acc[mi] = __builtin_amdgcn_mfma_f32_16x16x32_bf16(
                xv[lhalf * 256 + mi * 64 + lane], pb.v, acc[mi], 0, 0, 0);

        asm volatile("s_waitcnt vmcnt(0)");
        __syncthreads();
        cur ^= 1;
    }

    sum += __shfl_xor(sum, 16);
    sum += __shfl_xor(sum, 32);

    __syncthreads();                     // done with SH-as-Ks and Xs
    if (lhalf == 1) {
        float* cp = SH + (tsub * 64 + lane) * 17;
        #pragma unroll
        for (int mi = 0; mi < 4; ++mi)
            #pragma unroll
            for (int r = 0; r < 4; ++r) cp[mi * 4 + r] = acc[mi][r];
        cp[16] = sum;
    }
    __syncthreads();
    if (lhalf == 0) {
        const float* cp = SH + (tsub * 64 + lane) * 17;
        #pragma unroll
        for (int mi = 0; mi < 4; ++mi)
            #pragma unroll
            for (int r = 0; r < 4; ++r) acc[mi][r] += cp[mi * 4 + r];
        sum += cp[16];
        const float rinv = 1.0f / sum;
        #pragma unroll
        for (int mi = 0; mi < 4; ++mi) {
            #pragma unroll
            for (int r = 0; r < 4; ++r) {
                int d = mi * 16 + g * 4 + r;
                IV[((size_t)(bb * 512 + h * 64 + d)) * 1024 + t] = f2bf(acc[mi][r] * rinv);
            }
        }
    }
}

// ---------------- Kernel C: out = IV @ W_w^T + W_b ----------------
// Fused M=4096, tile 128m x 128n, BK=32, 4-buffer global_load_lds pipeline with
// counted vmcnt (2 stages in flight, never drains to 0 mid-loop) + one raw
// s_barrier per K-step. XOR slot swizzle = proven round-7/8 involution.
// grid (8 jt, 32 mt) = 256 blocks (1/CU), block 512 = 8 waves, wave 64x32.
__global__ __launch_bounds__(512) void gemm_out(const unsigned short* __restrict__ IV,
                                                const unsigned short* __restrict__ Wbf,
                                                const float* __restrict__ W_b,
                                                float* __restrict__ out) {
    const int jt = blockIdx.x;      // 0..7  (128 cols each)
    const int mt = blockIdx.y;      // 0..31 (128 rows each)
    const int tid = threadIdx.x;
    const int w = tid >> 6, lane = tid & 63;
    const int lr = lane & 15, kg = lane >> 4;
    const int wr = w >> 2, wc = w & 3;      // wave tile: rows wr*64, cols wc*32

    __shared__ unsigned short As[4][8192];   // 4 x 8KB  (128 rows x 32 k)
    __shared__ unsigned short Bs[4][8192];   // 4 x 8KB

    // staging: thread tid covers chunk (row=tid>>2, phys slot=tid&3);
    // kg_written = slot ^ ((row>>1)&3)  (same involution as read side).
    const int r0 = tid >> 2, s0 = tid & 3;   // r0 0..127
    const int kga = s0 ^ ((r0 >> 1) & 3);
    const unsigned short* Ag = IV  + (size_t)(mt * 128 + r0) * 1024 + kga * 8;
    const unsigned short* Bg = Wbf + (size_t)(jt * 128 + r0) * 1024 + kga * 8;

#define STAGE(bufi, kk) do {                                                                           \
    __builtin_amdgcn_global_load_lds((glb_u32*)(Ag + (kk)), (lds_u32*)(&As[bufi][tid * 8]), 16, 0, 0); \
    __builtin_amdgcn_global_load_lds((glb_u32*)(Bg + (kk)), (lds_u32*)(&Bs[bufi][tid * 8]), 16, 0, 0); \
} while (0)

    f32x4 acc[4][2];
    #pragma unroll
    for (int mi = 0; mi < 4; ++mi)
        #pragma unroll
        for (int ni = 0; ni < 2; ++ni)
            acc[mi][ni] = (f32x4){0.f, 0.f, 0.f, 0.f};

    STAGE(0, 0);
    STAGE(1, 32);
    STAGE(2, 64);

    const int slot = kg ^ ((lr >> 1) & 3);        // read-side involution (matches write)

    #pragma unroll
    for (int kt = 0; kt < 32; ++kt) {
        // Wait own stage-kt loads (2/wave), keep stages kt+1,kt+2 (4) in flight.
        if (kt < 30)       asm volatile("s_waitcnt vmcnt(4)" ::: "memory");
        else if (kt == 30) asm volatile("s_waitcnt vmcnt(2)" ::: "memory");
        else               asm volatile("s_waitcnt vmcnt(0)" ::: "memory");
        __builtin_amdgcn_s_barrier();              // all waves' stage-kt data visible
        __builtin_amdgcn_sched_barrier(0);         // pin: no ds_read hoisted above barrier
        // Issue stage kt+3 into buf (kt+3)&3 == (kt-1)&3 -- last read at iter kt-1,
        // whose ds_reads were consumed (lgkmcnt-waited by MFMAs) before this barrier.
        if (kt < 29) STAGE((kt + 3) & 3, (kt + 3) * 32);

        const int cur = kt & 3;
        bf16x8 af[4], bfr[2];
        #pragma unroll
        for (int mi = 0; mi < 4; ++mi) {
            int row = wr * 64 + mi * 16 + lr;
            af[mi] = *(const bf16x8*)(&As[cur][row * 32 + slot * 8]);
        }
        #pragma unroll
        for (int ni = 0; ni < 2; ++ni) {
            int row = wc * 32 + ni * 16 + lr;
            bfr[ni] = *(const bf16x8*)(&Bs[cur][row * 32 + slot * 8]);
        }
        #pragma unroll
        for (int mi = 0; mi < 4; ++mi)
            #pragma unroll
            for (int ni = 0; ni < 2; ++ni)
                acc[mi][ni] = __builtin_amdgcn_mfma_f32_16x16x32_bf16(
                    af[mi], bfr[ni], acc[mi][ni], 0, 0, 0);
    }
#undef STAGE

    float wb[2];
    #pragma unroll
    for (int ni = 0; ni < 2; ++ni) wb[ni] = W_b[jt * 128 + wc * 32 + ni * 16 + lr];

    #pragma unroll
    for (int mi = 0; mi < 4; ++mi) {
        #pragma unroll
        for (int ni = 0; ni < 2; ++ni) {
            #pragma unroll
            for (int r = 0; r < 4; ++r) {
                int m = mt * 128 + wr * 64 + mi * 16 + kg * 4 + r;   // fused row b*512+c
                int j = jt * 128 + wc * 32 + ni * 16 + lr;
                out[(size_t)m * 1024 + j] = acc[mi][ni][r] + wb[ni];
            }
        }
    }
}

extern "C" void kernel_launch(void* const* d_in, const int* in_sizes, int n_in,
                              void* d_out, int out_size, void* d_ws, size_t ws_size,
                              hipStream_t stream) {
    const float* X      = (const float*)d_in[0];
    const float* Wq_w   = (const float*)d_in[1];
    const float* Wq_b   = (const float*)d_in[2];
    const float* Wk_w   = (const float*)d_in[3];
    const float* Wk_b   = (const float*)d_in[4];
    const float* Wkey   = (const float*)d_in[5];
    const float* u      = (const float*)d_in[6];
    // d_in[7] = R : analytically reconstructed, never read
    const float* center = (const float*)d_in[8];
    const float* alpha  = (const float*)d_in[9];
    const float* W_w    = (const float*)d_in[10];
    const float* W_b    = (const float*)d_in[11];
    float* out = (float*)d_out;

    // Workspace layout (12 MB, no aliasing; proven ws_size >= 12.25 MB):
    //   0..1 MB   : XtP (bf16 packed fragments)
    //   1..1.5 MB : Q
    //   1.5..2 MB : K
    //   2..4 MB   : Wbf
    //   4..12 MB  : IV
    char* ws = (char*)d_ws;
    unsigned short* XtP  = (unsigned short*)ws;                      // 1 MB
    float*          Qbuf = (float*)(ws + (1024u << 10));             // 512 KB
    float*          Kbuf = (float*)(ws + (1536u << 10));             // 512 KB
    unsigned short* Wbf  = (unsigned short*)(ws + (2048u << 10));    // 2 MB
    unsigned short* IV   = (unsigned short*)(ws + (4096u << 10));    // 8 MB

    prep_fused<<<2176, 256, 0, stream>>>(X, Wq_w, Wq_b, Wk_w, Wk_b, W_w, Qbuf, Kbuf, XtP, Wbf);
    attn_mfma<<<dim3(16, 8, 8), 512, 0, stream>>>(XtP, Qbuf, Kbuf, u, Wkey, center, alpha, IV);
    gemm_out<<<dim3(8, 32), 512, 0, stream>>>(IV, Wbf, W_b, out);
}

// Round 10
// 136.242 us; speedup vs baseline: 3.4532x; 1.0279x over previous
//
#include <hip/hip_runtime.h>
#include <hip/hip_bf16.h>

#define BS   8
#define TT   1024
#define DIN  64
#define NH   8
#define DOUT 1024

typedef __attribute__((ext_vector_type(8))) short bf16x8;
typedef __attribute__((ext_vector_type(8))) unsigned short u16x8;
typedef __attribute__((ext_vector_type(4))) float f32x4;

typedef __attribute__((address_space(3))) unsigned int lds_u32;
typedef const __attribute__((address_space(1))) unsigned int glb_u32;

__device__ __forceinline__ unsigned short f2bf(float f) {
    unsigned int u = __float_as_uint(f);
    u += 0x7fff + ((u >> 16) & 1);          // RNE
    return (unsigned short)(u >> 16);
}

// ---------------- Kernel A: fused prep ----------------
// blocks 0..1023   : qk projection (8 rows each)
// blocks 1024..1151: X -> XtP packed-fragment bf16 transpose
// blocks 1152..2175: W_w -> bf16
__global__ __launch_bounds__(256) void prep_fused(const float* __restrict__ X,
                                                  const float* __restrict__ Wq_w,
                                                  const float* __restrict__ Wq_b,
                                                  const float* __restrict__ Wk_w,
                                                  const float* __restrict__ Wk_b,
                                                  const float* __restrict__ W_w,
                                                  float* __restrict__ Q,
                                                  float* __restrict__ K,
                                                  unsigned short* __restrict__ XtP,
                                                  unsigned short* __restrict__ Wbf) {
    __shared__ float Ws[32][65];
    __shared__ float bsm[32];
    __shared__ float Xs[8][64];
    __shared__ unsigned short S[64][68];

    const int bid = blockIdx.x, tid = threadIdx.x;

    if (bid < 1024) {
        // ---- qk projection ----
        for (int i = tid; i < 2048; i += 256) {
            int r = i >> 6, d = i & 63;
            Ws[r][d] = (r < 16) ? Wq_w[r * 64 + d] : Wk_w[(r - 16) * 64 + d];
        }
        if (tid < 32) bsm[tid] = (tid < 16) ? Wq_b[tid] : Wk_b[tid - 16];
        int row0 = bid * 8;
        for (int i = tid; i < 512; i += 256) {
            int r = i >> 6, d = i & 63;
            Xs[r][d] = X[(size_t)(row0 + r) * 64 + d];
        }
        __syncthreads();
        int r = tid >> 5;
        int j = tid & 31;
        float s = bsm[j];
        #pragma unroll
        for (int d = 0; d < 64; ++d) s = fmaf(Xs[r][d], Ws[j][d], s);
        int row = row0 + r;
        if (j < 16) {
            Q[(size_t)row * 16 + j] = s;
        } else {
            int h = (j - 16) >> 1, d2 = (j - 16) & 1;
            int b = row >> 10, l = row & 1023;
            K[(((size_t)(b * 8 + h)) * 1024 + l) * 2 + d2] = s;
        }
    } else if (bid < 1152) {
        // ---- XtP pack: chunk ((bb*32+lblk)*4+mi)*64+lane holds
        //      X[bb][lblk*32 + (lane>>4)*8 + j][mi*16 + (lane&15)], j=0..7
        int idx = bid - 1024;            // 0..127
        int bb = idx >> 4, lc = idx & 15;
        int l0 = lc * 64;
        int r = tid >> 4;                // 0..15
        int q4 = (tid & 15) * 4;
        #pragma unroll
        for (int p = 0; p < 4; ++p) {
            int row = p * 16 + r;
            float4 v = *(const float4*)(X + ((size_t)(bb * 1024 + l0 + row)) * 64 + q4);
            S[row][q4 + 0] = f2bf(v.x);
            S[row][q4 + 1] = f2bf(v.y);
            S[row][q4 + 2] = f2bf(v.z);
            S[row][q4 + 3] = f2bf(v.w);
        }
        __syncthreads();
        #pragma unroll
        for (int it = 0; it < 2; ++it) {
            int chunk = it * 256 + tid;
            int lane = chunk & 63, mi = (chunk >> 6) & 3, lbr = chunk >> 8;
            int g = lane >> 4, tr = lane & 15;
            int d = mi * 16 + tr;
            int ls = lbr * 32 + g * 8;
            u16x8 o;
            #pragma unroll
            for (int j = 0; j < 8; ++j) o[j] = S[ls + j][d];
            *(u16x8*)(XtP + (size_t)((((bb * 32 + lc * 2 + lbr) * 4 + mi) * 64 + lane)) * 8) = o;
        }
    } else {
        // ---- W_w -> bf16 ----
        int i = (bid - 1152) * 256 + tid;
        float4 v = ((const float4*)W_w)[i];
        ushort4 o;
        o.x = f2bf(v.x); o.y = f2bf(v.y); o.z = f2bf(v.z); o.w = f2bf(v.w);
        ((ushort4*)Wbf)[i] = o;
    }
}

// ---------------- Kernel B: scores + analytic-max softmax + MFMA PV ----------------
// grid (16 t-blocks, 8 h, 8 b), block 512 = 8 waves = 4 t-subtiles x 2 l-halves.
// X fragments staged per block via a 3-buffer global_load_lds pipeline with
// counted vmcnt (never drains to 0 mid-loop; gemm-proven template). Post-loop
// the lhalf partials are combined through LDS overlaid on the dead X buffers.
__global__ __launch_bounds__(512, 8) void attn_mfma(const unsigned short* __restrict__ XtP,
                                                    const float* __restrict__ Q,
                                                    const float* __restrict__ K,
                                                    const float* __restrict__ u,
                                                    const float* __restrict__ Wkey,
                                                    const float* __restrict__ center,
                                                    const float* __restrict__ alpha,
                                                    unsigned short* __restrict__ IV) {
    const int h  = blockIdx.y;
    const int bb = blockIdx.z;
    const int tid = threadIdx.x;
    const int w = tid >> 6, lane = tid & 63;
    const int g = lane >> 4, tr = lane & 15;
    const int tsub = w & 3, lhalf = w >> 2;
    const int t = blockIdx.x * 64 + tsub * 16 + tr;

    __shared__ float Ks[2048];               // 8 KB: K[l][2] for this (b,h)
    __shared__ unsigned short Xs[3][4096];   // 3 x 8 KB X-fragment buffers
    __shared__ float red[8][4];
    float* Cc = (float*)&Xs[0][0];           // post-loop combine overlay (17408B <= 24576B)

    // staging source: thread tid covers chunk (tid&255) of lblk {it | 16+it}
    const unsigned short* xsrc = XtP + (size_t)bb * 65536
                               + (size_t)((tid >> 8) * 16) * 2048 + (tid & 255) * 8;

    {   // K -> LDS (register path; compiler inserts the waits)
        const float4* Kg = (const float4*)(K + ((size_t)(bb * 8 + h)) * 2048);
        ((float4*)Ks)[tid] = Kg[tid];
    }
    __syncthreads();

    // block-wide K extrema for the analytic max bound
    float mxp, mxn, myp, myn;
    {
        const float2* K2 = (const float2*)Ks;
        float2 ka = K2[tid], kb = K2[tid + 512];
        mxp = fmaxf(ka.x, kb.x); mxn = fminf(ka.x, kb.x);
        myp = fmaxf(ka.y, kb.y); myn = fminf(ka.y, kb.y);
        #pragma unroll
        for (int off = 32; off; off >>= 1) {
            mxp = fmaxf(mxp, __shfl_xor(mxp, off)); mxn = fminf(mxn, __shfl_xor(mxn, off));
            myp = fmaxf(myp, __shfl_xor(myp, off)); myn = fminf(myn, __shfl_xor(myn, off));
        }
        if (lane == 0) { red[w][0] = mxp; red[w][1] = mxn; red[w][2] = myp; red[w][3] = myn; }
    }
    __syncthreads();
    mxp = red[0][0]; mxn = red[0][1]; myp = red[0][2]; myn = red[0][3];
    #pragma unroll
    for (int i = 1; i < 8; ++i) {
        mxp = fmaxf(mxp, red[i][0]); mxn = fminf(mxn, red[i][1]);
        myp = fmaxf(myp, red[i][2]); myn = fminf(myn, red[i][3]);
    }

    const float L2E = 1.4426950408889634f;
    float2 q  = ((const float2*)Q)[(size_t)(bb * 1024 + t) * 8 + h];
    float2 uu = ((const float2*)u)[t];
    const float al = alpha[0];
    const float a0 = (q.x + uu.x) * L2E;
    const float a1 = (q.y + uu.y) * L2E;
    const float p0 = q.x - al;
    const float p1 = q.y + 2.0f * al * center[h];
    const float c0 = (p0 * Wkey[0] + p1 * Wkey[2]) * L2E;
    const float c1 = (p0 * Wkey[1] + p1 * Wkey[3]) * L2E;
    const float tf = (float)t;

    // analytic upper bound on max score
    const float qb = fmaxf(a0 * mxp, a0 * mxn) + fmaxf(a1 * myp, a1 * myn);
    const float dlo = -tf, dhi = 1023.0f - tf;
    float qm = fmaxf(fmaf(fmaf(c0, dlo, c1), dlo, 0.0f),
                     fmaf(fmaf(c0, dhi, c1), dhi, 0.0f));
    if (c0 < 0.0f) {
        float dstar = -c1 / (2.0f * c0);
        if (dstar > dlo && dstar < dhi) qm = -c1 * c1 / (4.0f * c0);
    }
    const float negm = -(qm + qb);

    f32x4 acc[4];
    #pragma unroll
    for (int mi = 0; mi < 4; ++mi) acc[mi] = (f32x4){0.f, 0.f, 0.f, 0.f};
    float sum = 0.f;

#define XSTAGE(bufi, itx) \
    __builtin_amdgcn_global_load_lds((glb_u32*)(xsrc + (itx) * 2048), \
                                     (lds_u32*)(&Xs[bufi][tid * 8]), 16, 0, 0)

    XSTAGE(0, 0);
    XSTAGE(1, 1);

    #pragma unroll
    for (int it = 0; it < 16; ++it) {
        // Wait own stage-it load (1/thread), keep stage it+1 in flight.
        if (it < 15) asm volatile("s_waitcnt vmcnt(1)" ::: "memory");
        else         asm volatile("s_waitcnt vmcnt(0)" ::: "memory");
        __builtin_amdgcn_s_barrier();              // stage-it data visible block-wide
        __builtin_amdgcn_sched_barrier(0);         // no ds_read hoisted above barrier
        // Stage it+2 into buf (it+2)%3: last read at iter it-1, whose ds_reads
        // were register-consumed (lgkmcnt-waited by MFMAs) before this barrier.
        if (it < 14) XSTAGE((it + 2) % 3, it + 2);

        const int cur = it % 3;
        const int lb = lhalf * 512 + it * 32 + g * 8;
        const float4* kp = (const float4*)Ks + (lb >> 1);   // {x0,y0,x1,y1}
        const float dlb = (float)lb - tf;
        union { bf16x8 v; unsigned int wd[4]; } pb;
        #pragma unroll
        for (int jj = 0; jj < 4; ++jj) {
            float4 kv = kp[jj];
            float dl0 = dlb + (float)(2 * jj);
            float dl1 = dl0 + 1.0f;
            float e0 = exp2f(fmaf(fmaf(c0, dl0, c1), dl0, fmaf(a0, kv.x, fmaf(a1, kv.y, negm))));
            float e1 = exp2f(fmaf(fmaf(c0, dl1, c1), dl1, fmaf(a0, kv.z, fmaf(a1, kv.w, negm))));
            sum += e0 + e1;
            asm("v_cvt_pk_bf16_f32 %0, %1, %2" : "=v"(pb.wd[jj]) : "v"(e0), "v"(e1));
        }
        const bf16x8* xv = (const bf16x8*)(&Xs[cur][0]);
        #pragma unroll
        for (int mi = 0; mi < 4; ++mi)
            acc[mi] = __builtin_amdgcn_mfma_f32_16x16x32_bf16(
                xv[lhalf * 256 + mi * 64 + lane], pb.v, acc[mi], 0, 0, 0);
    }
#undef XSTAGE

    sum += __shfl_xor(sum, 16);
    sum += __shfl_xor(sum, 32);

    __syncthreads();                     // all reads of Xs done -> Cc overlay safe
    if (lhalf == 1) {
        float* cp = Cc + (tsub * 64 + lane) * 17;
        #pragma unroll
        for (int mi = 0; mi < 4; ++mi)
            #pragma unroll
            for (int r = 0; r < 4; ++r) cp[mi * 4 + r] = acc[mi][r];
        cp[16] = sum;
    }
    __syncthreads();
    if (lhalf == 0) {
        const float* cp = Cc + (tsub * 64 + lane) * 17;
        #pragma unroll
        for (int mi = 0; mi < 4; ++mi)
            #pragma unroll
            for (int r = 0; r < 4; ++r) acc[mi][r] += cp[mi * 4 + r];
        sum += cp[16];
        const float rinv = 1.0f / sum;
        #pragma unroll
        for (int mi = 0; mi < 4; ++mi) {
            #pragma unroll
            for (int r = 0; r < 4; ++r) {
                int d = mi * 16 + g * 4 + r;
                IV[((size_t)(bb * 512 + h * 64 + d)) * 1024 + t] = f2bf(acc[mi][r] * rinv);
            }
        }
    }
}

// ---------------- Kernel C: out = IV @ W_w^T + W_b ----------------
// Fused M=4096, tile 128m x 128n, BK=32, 4-buffer global_load_lds pipeline with
// counted vmcnt (2 stages in flight, never drains to 0 mid-loop) + one raw
// s_barrier per K-step. XOR slot swizzle = proven round-7/8 involution.
// grid (8 jt, 32 mt) = 256 blocks (1/CU), block 512 = 8 waves, wave 64x32.
__global__ __launch_bounds__(512) void gemm_out(const unsigned short* __restrict__ IV,
                                                const unsigned short* __restrict__ Wbf,
                                                const float* __restrict__ W_b,
                                                float* __restrict__ out) {
    const int jt = blockIdx.x;      // 0..7  (128 cols each)
    const int mt = blockIdx.y;      // 0..31 (128 rows each)
    const int tid = threadIdx.x;
    const int w = tid >> 6, lane = tid & 63;
    const int lr = lane & 15, kg = lane >> 4;
    const int wr = w >> 2, wc = w & 3;      // wave tile: rows wr*64, cols wc*32

    __shared__ unsigned short As[4][8192];   // 4 x 8KB  (128 rows x 32 k)
    __shared__ unsigned short Bs[4][8192];   // 4 x 8KB

    // staging: thread tid covers chunk (row=tid>>2, phys slot=tid&3);
    // kg_written = slot ^ ((row>>1)&3)  (same involution as read side).
    const int r0 = tid >> 2, s0 = tid & 3;   // r0 0..127
    const int kga = s0 ^ ((r0 >> 1) & 3);
    const unsigned short* Ag = IV  + (size_t)(mt * 128 + r0) * 1024 + kga * 8;
    const unsigned short* Bg = Wbf + (size_t)(jt * 128 + r0) * 1024 + kga * 8;

#define STAGE(bufi, kk) do {                                                                           \
    __builtin_amdgcn_global_load_lds((glb_u32*)(Ag + (kk)), (lds_u32*)(&As[bufi][tid * 8]), 16, 0, 0); \
    __builtin_amdgcn_global_load_lds((glb_u32*)(Bg + (kk)), (lds_u32*)(&Bs[bufi][tid * 8]), 16, 0, 0); \
} while (0)

    f32x4 acc[4][2];
    #pragma unroll
    for (int mi = 0; mi < 4; ++mi)
        #pragma unroll
        for (int ni = 0; ni < 2; ++ni)
            acc[mi][ni] = (f32x4){0.f, 0.f, 0.f, 0.f};

    STAGE(0, 0);
    STAGE(1, 32);
    STAGE(2, 64);

    const int slot = kg ^ ((lr >> 1) & 3);        // read-side involution (matches write)

    #pragma unroll
    for (int kt = 0; kt < 32; ++kt) {
        // Wait own stage-kt loads (2/wave), keep stages kt+1,kt+2 (4) in flight.
        if (kt < 30)       asm volatile("s_waitcnt vmcnt(4)" ::: "memory");
        else if (kt == 30) asm volatile("s_waitcnt vmcnt(2)" ::: "memory");
        else               asm volatile("s_waitcnt vmcnt(0)" ::: "memory");
        __builtin_amdgcn_s_barrier();              // all waves' stage-kt data visible
        __builtin_amdgcn_sched_barrier(0);         // pin: no ds_read hoisted above barrier
        // Issue stage kt+3 into buf (kt+3)&3 == (kt-1)&3 -- last read at iter kt-1,
        // whose ds_reads were consumed (lgkmcnt-waited by MFMAs) before this barrier.
        if (kt < 29) STAGE((kt + 3) & 3, (kt + 3) * 32);

        const int cur = kt & 3;
        bf16x8 af[4], bfr[2];
        #pragma unroll
        for (int mi = 0; mi < 4; ++mi) {
            int row = wr * 64 + mi * 16 + lr;
            af[mi] = *(const bf16x8*)(&As[cur][row * 32 + slot * 8]);
        }
        #pragma unroll
        for (int ni = 0; ni < 2; ++ni) {
            int row = wc * 32 + ni * 16 + lr;
            bfr[ni] = *(const bf16x8*)(&Bs[cur][row * 32 + slot * 8]);
        }
        #pragma unroll
        for (int mi = 0; mi < 4; ++mi)
            #pragma unroll
            for (int ni = 0; ni < 2; ++ni)
                acc[mi][ni] = __builtin_amdgcn_mfma_f32_16x16x32_bf16(
                    af[mi], bfr[ni], acc[mi][ni], 0, 0, 0);
    }
#undef STAGE

    float wb[2];
    #pragma unroll
    for (int ni = 0; ni < 2; ++ni) wb[ni] = W_b[jt * 128 + wc * 32 + ni * 16 + lr];

    #pragma unroll
    for (int mi = 0; mi < 4; ++mi) {
        #pragma unroll
        for (int ni = 0; ni < 2; ++ni) {
            #pragma unroll
            for (int r = 0; r < 4; ++r) {
                int m = mt * 128 + wr * 64 + mi * 16 + kg * 4 + r;   // fused row b*512+c
                int j = jt * 128 + wc * 32 + ni * 16 + lr;
                out[(size_t)m * 1024 + j] = acc[mi][ni][r] + wb[ni];
            }
        }
    }
}

extern "C" void kernel_launch(void* const* d_in, const int* in_sizes, int n_in,
                              void* d_out, int out_size, void* d_ws, size_t ws_size,
                              hipStream_t stream) {
    const float* X      = (const float*)d_in[0];
    const float* Wq_w   = (const float*)d_in[1];
    const float* Wq_b   = (const float*)d_in[2];
    const float* Wk_w   = (const float*)d_in[3];
    const float* Wk_b   = (const float*)d_in[4];
    const float* Wkey   = (const float*)d_in[5];
    const float* u      = (const float*)d_in[6];
    // d_in[7] = R : analytically reconstructed, never read
    const float* center = (const float*)d_in[8];
    const float* alpha  = (const float*)d_in[9];
    const float* W_w    = (const float*)d_in[10];
    const float* W_b    = (const float*)d_in[11];
    float* out = (float*)d_out;

    // Workspace layout (12 MB, no aliasing; proven ws_size >= 12.25 MB):
    //   0..1 MB   : XtP (bf16 packed fragments)
    //   1..1.5 MB : Q
    //   1.5..2 MB : K
    //   2..4 MB   : Wbf
    //   4..12 MB  : IV
    char* ws = (char*)d_ws;
    unsigned short* XtP  = (unsigned short*)ws;                      // 1 MB
    float*          Qbuf = (float*)(ws + (1024u << 10));             // 512 KB
    float*          Kbuf = (float*)(ws + (1536u << 10));             // 512 KB
    unsigned short* Wbf  = (unsigned short*)(ws + (2048u << 10));    // 2 MB
    unsigned short* IV   = (unsigned short*)(ws + (4096u << 10));    // 8 MB

    prep_fused<<<2176, 256, 0, stream>>>(X, Wq_w, Wq_b, Wk_w, Wk_b, W_w, Qbuf, Kbuf, XtP, Wbf);
    attn_mfma<<<dim3(16, 8, 8), 512, 0, stream>>>(XtP, Qbuf, Kbuf, u, Wkey, center, alpha, IV);
    gemm_out<<<dim3(8, 32), 512, 0, stream>>>(IV, Wbf, W_b, out);
}